// Round 1
// baseline (3931.314 us; speedup 1.0000x reference)
//
#include <hip/hip_runtime.h>

#define N_NODES 100000
#define N_EDGES 3200000
#define BGR 64
#define DIM 16
#define NFP 33
#define EMB 128
#define MAXLEN 3000
#define LOCLEN 2998
#define NF 32
#define KS 8
#define OUTT 121
#define FC_IN 3872
#define BN_EPSV 1e-5f

// ---------------- CSR build ----------------
__global__ void k_count(const int* __restrict__ dst, int* __restrict__ cnt) {
    int i = blockIdx.x * blockDim.x + threadIdx.x;
    if (i < N_EDGES) atomicAdd(&cnt[dst[i]], 1);
}

__global__ void k_scan(const int* __restrict__ cnt, int* __restrict__ ptr,
                       int* __restrict__ cursor) {
    __shared__ int part[1024];
    const int CH = (N_NODES + 1023) / 1024;  // 98
    int t = threadIdx.x;
    int base = t * CH;
    int s = 0;
    for (int i = 0; i < CH; i++) { int idx = base + i; if (idx < N_NODES) s += cnt[idx]; }
    part[t] = s;
    __syncthreads();
    for (int off = 1; off < 1024; off <<= 1) {
        int v = (t >= off) ? part[t - off] : 0;
        __syncthreads();
        part[t] += v;
        __syncthreads();
    }
    int run = (t == 0) ? 0 : part[t - 1];
    for (int i = 0; i < CH; i++) {
        int idx = base + i;
        if (idx < N_NODES) {
            int c = cnt[idx];
            ptr[idx] = run; cursor[idx] = run;
            run += c;
        }
    }
    if (t == 1023) ptr[N_NODES] = part[1023];
}

__global__ void k_scatter(const int* __restrict__ src, const int* __restrict__ dst,
                          const float* __restrict__ w, int* __restrict__ cursor,
                          int* __restrict__ src_s, float* __restrict__ w_s) {
    int i = blockIdx.x * blockDim.x + threadIdx.x;
    if (i < N_EDGES) {
        int d = dst[i];
        int p = atomicAdd(&cursor[d], 1);
        src_s[p] = src[i];
        w_s[p] = w[i];
    }
}

// ---------------- GINE layer 1 (33 -> 16), wave per node ----------------
__global__ void __launch_bounds__(256) k_gine1(
    const float* __restrict__ x, const int* __restrict__ ptr,
    const int* __restrict__ srcs, const float* __restrict__ wsv,
    const float* __restrict__ ew, const float* __restrict__ ebv,
    const float* __restrict__ epsp,
    const float* __restrict__ W1, const float* __restrict__ b1,
    const float* __restrict__ W2, const float* __restrict__ b2,
    float* __restrict__ z, float* __restrict__ bnstat) {
    __shared__ float s_sum[DIM], s_sq[DIM];
    int t = threadIdx.x;
    if (t < DIM) { s_sum[t] = 0.f; s_sq[t] = 0.f; }
    __syncthreads();
    int wave = t >> 6, lane = t & 63;
    int node = blockIdx.x * 4 + wave;
    if (node < N_NODES) {
        int f = lane;
        float h = 0.f;
        if (f < NFP) {
            float ewf = ew[f], ebf = ebv[f];
            float acc = 0.f;
            int e0 = ptr[node], e1 = ptr[node + 1];
            for (int i = e0; i < e1; i++) {
                int s = srcs[i]; float wv = wsv[i];
                float m = x[s * NFP + f] + wv * ewf + ebf;
                acc += fmaxf(m, 0.f);
            }
            h = (1.f + epsp[0]) * x[node * NFP + f] + acc;
        }
        int o = lane & 15;
        float tv = b1[o];
        #pragma unroll
        for (int ff = 0; ff < NFP; ff++) tv += __shfl(h, ff) * W1[ff * DIM + o];
        tv = fmaxf(tv, 0.f);
        float zv = b2[o];
        #pragma unroll
        for (int ff = 0; ff < DIM; ff++) zv += __shfl(tv, ff) * W2[ff * DIM + o];
        zv = fmaxf(zv, 0.f);
        if (lane < DIM) {
            z[node * DIM + o] = zv;
            atomicAdd(&s_sum[o], zv);
            atomicAdd(&s_sq[o], zv * zv);
        }
    }
    __syncthreads();
    if (t < DIM) { atomicAdd(&bnstat[t], s_sum[t]); atomicAdd(&bnstat[DIM + t], s_sq[t]); }
}

// ---------------- GINE layers 2-5 (16 -> 16), wave per node ----------------
__global__ void __launch_bounds__(256) k_gine16(
    const float* __restrict__ x, const int* __restrict__ ptr,
    const int* __restrict__ srcs, const float* __restrict__ wsv,
    const float* __restrict__ ew, const float* __restrict__ ebv,
    const float* __restrict__ epsp,
    const float* __restrict__ W1, const float* __restrict__ b1,
    const float* __restrict__ W2, const float* __restrict__ b2,
    float* __restrict__ z, float* __restrict__ bnstat) {
    __shared__ float s_sum[DIM], s_sq[DIM];
    int t = threadIdx.x;
    if (t < DIM) { s_sum[t] = 0.f; s_sq[t] = 0.f; }
    __syncthreads();
    int wave = t >> 6, lane = t & 63;
    int node = blockIdx.x * 4 + wave;
    if (node < N_NODES) {
        int e4 = lane >> 4, f = lane & 15;
        float ewf = ew[f], ebf = ebv[f];
        float acc = 0.f;
        int e0 = ptr[node], e1 = ptr[node + 1];
        for (int i = e0 + e4; i < e1; i += 4) {
            int s = srcs[i]; float wv = wsv[i];
            float m = x[s * DIM + f] + wv * ewf + ebf;
            acc += fmaxf(m, 0.f);
        }
        acc += __shfl_xor(acc, 16);
        acc += __shfl_xor(acc, 32);
        float h = (1.f + epsp[0]) * x[node * DIM + f] + acc;
        float tv = b1[f];
        #pragma unroll
        for (int ff = 0; ff < DIM; ff++) tv += __shfl(h, ff) * W1[ff * DIM + f];
        tv = fmaxf(tv, 0.f);
        float zv = b2[f];
        #pragma unroll
        for (int ff = 0; ff < DIM; ff++) zv += __shfl(tv, ff) * W2[ff * DIM + f];
        zv = fmaxf(zv, 0.f);
        if (lane < DIM) {
            z[node * DIM + f] = zv;
            atomicAdd(&s_sum[f], zv);
            atomicAdd(&s_sq[f], zv * zv);
        }
    }
    __syncthreads();
    if (t < DIM) { atomicAdd(&bnstat[t], s_sum[t]); atomicAdd(&bnstat[DIM + t], s_sq[t]); }
}

// ---------------- BN normalize (scale/shift computed from stats in-kernel) ----------------
__global__ void k_norm(const float* __restrict__ z, float* __restrict__ x,
                       const float* __restrict__ bnstat, const float* __restrict__ gamma,
                       const float* __restrict__ beta) {
    int i = blockIdx.x * blockDim.x + threadIdx.x;
    int base = i * 4;
    if (base >= N_NODES * DIM) return;
    float4 zv = *(const float4*)(z + base);
    float zz[4] = {zv.x, zv.y, zv.z, zv.w};
    float out[4];
    int f0 = base & 15;
    const float invn = 1.f / (float)N_NODES;
    #pragma unroll
    for (int j = 0; j < 4; j++) {
        int f = f0 + j;
        float mu = bnstat[f] * invn;
        float var = bnstat[DIM + f] * invn - mu * mu;
        float sc = gamma[f] * rsqrtf(var + BN_EPSV);
        float sh = beta[f] - mu * sc;
        out[j] = zz[j] * sc + sh;
    }
    *(float4*)(x + base) = make_float4(out[0], out[1], out[2], out[3]);
}

// ---------------- pooling + fc1_xp ----------------
__global__ void k_pool(const float* __restrict__ x, const int* __restrict__ batch,
                       float* __restrict__ gsum, float* __restrict__ gcnt) {
    int i = blockIdx.x * blockDim.x + threadIdx.x;
    if (i >= N_NODES * DIM) return;
    int n = i >> 4, f = i & 15;
    int b = batch[n];
    atomicAdd(&gsum[b * DIM + f], x[i]);
    if (f == 0) atomicAdd(&gcnt[b], 1.f);
}

__global__ void k_xp(const float* __restrict__ gsum, const float* __restrict__ gcnt,
                     const float* __restrict__ w, const float* __restrict__ bias,
                     float* __restrict__ out) {
    int b = blockIdx.x;
    int e = threadIdx.x;
    float inv = 1.f / fmaxf(gcnt[b], 1.f);
    float acc = bias[e];
    #pragma unroll
    for (int f = 0; f < DIM; f++) acc += gsum[b * DIM + f] * inv * w[f * EMB + e];
    out[b * EMB + e] = fmaxf(acc, 0.f);
}

// ---------------- RNA: token-bucketed conv weights ----------------
// W[b,o,v,k] = sum over l with tok[b,l]==v of cw[o,l,k]
__global__ void __launch_bounds__(256) k_wg(const int* __restrict__ tok,
                                            const float* __restrict__ cw,
                                            float* __restrict__ W) {
    int b = blockIdx.x;
    int t = threadIdx.x;  // 256 = 32 o x 8 k
    int o = t >> 3, k = t & 7;
    __shared__ int tk[256];
    float a0 = 0, a1 = 0, a2 = 0, a3 = 0, a4 = 0;
    const float* cwp = cw + o * (MAXLEN * KS) + k;
    for (int l0 = 0; l0 < MAXLEN; l0 += 256) {
        int lim = MAXLEN - l0; if (lim > 256) lim = 256;
        __syncthreads();
        if (t < lim) tk[t] = tok[b * MAXLEN + l0 + t];
        __syncthreads();
        for (int j = 0; j < lim; j++) {
            int v = tk[j];
            float c = cwp[(l0 + j) * KS];
            a0 += (v == 0) ? c : 0.f;
            a1 += (v == 1) ? c : 0.f;
            a2 += (v == 2) ? c : 0.f;
            a3 += (v == 3) ? c : 0.f;
            a4 += (v == 4) ? c : 0.f;
        }
    }
    float* Wp = W + ((b * NF + o) * 5) * KS + k;
    Wp[0 * KS] = a0; Wp[1 * KS] = a1; Wp[2 * KS] = a2; Wp[3 * KS] = a3; Wp[4 * KS] = a4;
}

__global__ void __launch_bounds__(128) k_wl(const int* __restrict__ tok,
                                            const float* __restrict__ cw,
                                            float* __restrict__ W) {
    int b = blockIdx.x;
    int half = blockIdx.y;
    int t = threadIdx.x;  // 128 = 16 o x 8 k
    int o = (t >> 3) + half * 16, k = t & 7;
    __shared__ float acc[128][65];
    __shared__ int tk[256];
    for (int v = 0; v < 65; v++) acc[t][v] = 0.f;
    const float* cwp = cw + o * (LOCLEN * KS) + k;
    for (int l0 = 0; l0 < LOCLEN; l0 += 256) {
        int lim = LOCLEN - l0; if (lim > 256) lim = 256;
        __syncthreads();
        for (int j = t; j < lim; j += 128) tk[j] = tok[b * LOCLEN + l0 + j];
        __syncthreads();
        for (int j = 0; j < lim; j++) {
            int v = tk[j];
            acc[t][v] += cwp[(l0 + j) * KS];
        }
    }
    float* Wp = W + ((b * NF + o) * 65) * KS + k;
    for (int v = 0; v < 65; v++) Wp[v * KS] = acc[t][v];
}

// y[b,o,t] = cb[o] + sum_{v,k} W[b,o,v,k]*emb[v,t+k]
__global__ void k_y(const float* __restrict__ Wg, const float* __restrict__ Wl,
                    const float* __restrict__ emb1, const float* __restrict__ emb2,
                    const float* __restrict__ cb1, const float* __restrict__ cb2,
                    float* __restrict__ yg, float* __restrict__ yl) {
    int which = blockIdx.y;
    int bo = blockIdx.x;
    int b = bo >> 5, o = bo & 31;
    int t = threadIdx.x;  // 128
    const float* W = which ? Wl : Wg;
    const float* emb = which ? emb2 : emb1;
    const float* cb = which ? cb2 : cb1;
    float* y = which ? yl : yg;
    int V = which ? 65 : 5;
    __shared__ float Wsh[65 * KS];
    const float* Wrow = W + (b * NF + o) * V * KS;
    for (int j = t; j < V * KS; j += 128) Wsh[j] = Wrow[j];
    __syncthreads();
    if (t < OUTT) {
        float acc = cb[o];
        for (int v = 0; v < V; v++) {
            const float* ep = emb + v * EMB + t;
            #pragma unroll
            for (int k = 0; k < KS; k++) acc += Wsh[v * KS + k] * ep[k];
        }
        y[(b * NF + o) * OUTT + t] = acc;
    }
}

__global__ void k_fc(const float* __restrict__ yg, const float* __restrict__ yl,
                     const float* __restrict__ w, const float* __restrict__ bias,
                     float* __restrict__ xrg, float* __restrict__ xrl) {
    int b = blockIdx.x;
    int which = blockIdx.y;
    const float* y = which ? yl : yg;
    float* xr = which ? xrl : xrg;
    int e = threadIdx.x;  // 128
    __shared__ float ych[128];
    float acc = bias[e];
    for (int j0 = 0; j0 < FC_IN; j0 += 128) {
        __syncthreads();
        int lim = FC_IN - j0; if (lim > 128) lim = 128;
        if (e < lim) ych[e] = y[b * FC_IN + j0 + e];
        __syncthreads();
        for (int jj = 0; jj < lim; jj++) acc += ych[jj] * w[(j0 + jj) * EMB + e];
    }
    xr[b * EMB + e] = acc;
}

__global__ void k_comb(const float* __restrict__ xrg, const float* __restrict__ xrl,
                       float* __restrict__ out) {
    int i = blockIdx.x * blockDim.x + threadIdx.x;
    if (i < BGR * EMB) out[i] = 0.5f * (xrg[i] + xrl[i]);
}

extern "C" void kernel_launch(void* const* d_in, const int* in_sizes, int n_in,
                              void* d_out, int out_size, void* d_ws, size_t ws_size,
                              hipStream_t stream) {
    const float* pro_x = (const float*)d_in[0];
    const int* eidx = (const int*)d_in[1];
    const int* esrc = eidx;
    const int* edst = eidx + N_EDGES;
    const float* pw = (const float*)d_in[2];
    const int* batch = (const int*)d_in[3];
    const int* rg = (const int*)d_in[4];
    const int* rl = (const int*)d_in[5];
    const float* g1_w1 = (const float*)d_in[6];
    const float* g1_b1 = (const float*)d_in[7];
    const float* g1_w2 = (const float*)d_in[8];
    const float* g1_b2 = (const float*)d_in[9];
    const float* g1_ew = (const float*)d_in[10];
    const float* g1_eb = (const float*)d_in[11];
    const float* g1_eps = (const float*)d_in[12];
    const float* g_w1 = (const float*)d_in[13];
    const float* g_b1 = (const float*)d_in[14];
    const float* g_w2 = (const float*)d_in[15];
    const float* g_b2 = (const float*)d_in[16];
    const float* g_ew = (const float*)d_in[17];
    const float* g_eb = (const float*)d_in[18];
    const float* g_eps = (const float*)d_in[19];
    const float* bn_gamma = (const float*)d_in[20];
    const float* bn_beta = (const float*)d_in[21];
    const float* fc1_xp_w = (const float*)d_in[22];
    const float* fc1_xp_b = (const float*)d_in[23];
    const float* emb1 = (const float*)d_in[24];
    const float* emb2 = (const float*)d_in[25];
    const float* convr1_w = (const float*)d_in[26];
    const float* convr1_b = (const float*)d_in[27];
    const float* convr2_w = (const float*)d_in[28];
    const float* convr2_b = (const float*)d_in[29];
    const float* fcxr_w = (const float*)d_in[30];
    const float* fcxr_b = (const float*)d_in[31];
    float* out = (float*)d_out;

    // workspace carve (word offsets, all 256B aligned)
    float* wsf = (float*)d_ws;
    int* ptr     = (int*)wsf;          wsf += 100096;   // N+1
    int* cnt     = (int*)wsf;          wsf += 100096;
    int* cursor  = (int*)wsf;          wsf += 100096;
    int* src_s   = (int*)wsf;          wsf += N_EDGES;
    float* w_s   = wsf;                wsf += N_EDGES;
    float* xA    = wsf;                wsf += N_NODES * DIM;
    float* xB    = wsf;                wsf += N_NODES * DIM;
    float* stats = wsf;                wsf += 1280;     // gsum[1024] gcnt[64] bnstat[5*32]
    float* Wg    = wsf;                wsf += BGR * NF * 5 * KS;
    float* Wl    = wsf;                wsf += BGR * NF * 65 * KS;
    float* yg    = wsf;                wsf += BGR * NF * OUTT;  // 247808
    float* yl    = wsf;                wsf += BGR * NF * OUTT;
    float* xrg   = wsf;                wsf += BGR * EMB;
    float* xrl   = wsf;                wsf += BGR * EMB;
    float* gsum   = stats;
    float* gcnt   = stats + 1024;
    float* bnstat = stats + 1088;

    hipMemsetAsync(cnt, 0, N_NODES * sizeof(int), stream);
    hipMemsetAsync(stats, 0, 1280 * sizeof(float), stream);

    // CSR build
    k_count<<<N_EDGES / 256, 256, 0, stream>>>(edst, cnt);
    k_scan<<<1, 1024, 0, stream>>>(cnt, ptr, cursor);
    k_scatter<<<N_EDGES / 256, 256, 0, stream>>>(esrc, edst, pw, cursor, src_s, w_s);

    // RNA branch
    k_wg<<<BGR, 256, 0, stream>>>(rg, convr1_w, Wg);
    k_wl<<<dim3(BGR, 2), 128, 0, stream>>>(rl, convr2_w, Wl);
    k_y<<<dim3(BGR * NF, 2), 128, 0, stream>>>(Wg, Wl, emb1, emb2, convr1_b, convr2_b, yg, yl);
    k_fc<<<dim3(BGR, 2), 128, 0, stream>>>(yg, yl, fcxr_w, fcxr_b, xrg, xrl);
    k_comb<<<(BGR * EMB + 255) / 256, 256, 0, stream>>>(xrg, xrl, out);

    // GNN stack
    int gblocks = (N_NODES + 3) / 4;
    int nblocks = (N_NODES * DIM / 4 + 255) / 256;
    k_gine1<<<gblocks, 256, 0, stream>>>(pro_x, ptr, src_s, w_s, g1_ew, g1_eb, g1_eps,
                                         g1_w1, g1_b1, g1_w2, g1_b2, xB, bnstat);
    k_norm<<<nblocks, 256, 0, stream>>>(xB, xA, bnstat, bn_gamma, bn_beta);
    for (int i = 0; i < 4; i++) {
        k_gine16<<<gblocks, 256, 0, stream>>>(xA, ptr, src_s, w_s,
                                              g_ew + i * DIM, g_eb + i * DIM, g_eps + i,
                                              g_w1 + i * DIM * DIM, g_b1 + i * DIM,
                                              g_w2 + i * DIM * DIM, g_b2 + i * DIM,
                                              xB, bnstat + (i + 1) * 32);
        k_norm<<<nblocks, 256, 0, stream>>>(xB, xA, bnstat + (i + 1) * 32,
                                            bn_gamma + (i + 1) * DIM, bn_beta + (i + 1) * DIM);
    }
    k_pool<<<(N_NODES * DIM + 255) / 256, 256, 0, stream>>>(xA, batch, gsum, gcnt);
    k_xp<<<BGR, EMB, 0, stream>>>(gsum, gcnt, fc1_xp_w, fc1_xp_b, out + BGR * EMB);
}

// Round 2
// 3203.779 us; speedup vs baseline: 1.2271x; 1.2271x over previous
//
#include <hip/hip_runtime.h>

#define N_NODES 100000
#define N_EDGES 3200000
#define BGR 64
#define DIM 16
#define NFP 33
#define EMB 128
#define MAXLEN 3000
#define LOCLEN 2998
#define NF 32
#define KS 8
#define OUTT 121
#define FC_IN 3872
#define BN_EPSV 1e-5f
#define POOL_CHUNK 2048

// ---------------- CSR build ----------------
__global__ void k_count(const int* __restrict__ dst, int* __restrict__ cnt) {
    int i = blockIdx.x * blockDim.x + threadIdx.x;
    if (i < N_EDGES) atomicAdd(&cnt[dst[i]], 1);
}

__global__ void k_scan(const int* __restrict__ cnt, int* __restrict__ ptr,
                       int* __restrict__ cursor) {
    __shared__ int part[1024];
    const int CH = (N_NODES + 1023) / 1024;  // 98
    int t = threadIdx.x;
    int base = t * CH;
    int s = 0;
    for (int i = 0; i < CH; i++) { int idx = base + i; if (idx < N_NODES) s += cnt[idx]; }
    part[t] = s;
    __syncthreads();
    for (int off = 1; off < 1024; off <<= 1) {
        int v = (t >= off) ? part[t - off] : 0;
        __syncthreads();
        part[t] += v;
        __syncthreads();
    }
    int run = (t == 0) ? 0 : part[t - 1];
    for (int i = 0; i < CH; i++) {
        int idx = base + i;
        if (idx < N_NODES) {
            int c = cnt[idx];
            ptr[idx] = run; cursor[idx] = run;
            run += c;
        }
    }
    if (t == 1023) ptr[N_NODES] = part[1023];
}

__global__ void k_scatter(const int* __restrict__ src, const int* __restrict__ dst,
                          const float* __restrict__ w, int* __restrict__ cursor,
                          int* __restrict__ src_s, float* __restrict__ w_s) {
    int i = blockIdx.x * blockDim.x + threadIdx.x;
    if (i < N_EDGES) {
        int d = dst[i];
        int p = atomicAdd(&cursor[d], 1);
        src_s[p] = src[i];
        w_s[p] = w[i];
    }
}

// ---------------- GINE layer 1 (33 -> 16), wave per node ----------------
__global__ void __launch_bounds__(256) k_gine1(
    const float* __restrict__ x, const int* __restrict__ ptr,
    const int* __restrict__ srcs, const float* __restrict__ wsv,
    const float* __restrict__ ew, const float* __restrict__ ebv,
    const float* __restrict__ epsp,
    const float* __restrict__ W1, const float* __restrict__ b1,
    const float* __restrict__ W2, const float* __restrict__ b2,
    float* __restrict__ z, float* __restrict__ bnstat) {
    __shared__ float s_sum[DIM], s_sq[DIM];
    int t = threadIdx.x;
    if (t < DIM) { s_sum[t] = 0.f; s_sq[t] = 0.f; }
    __syncthreads();
    int wave = t >> 6, lane = t & 63;
    int node = blockIdx.x * 4 + wave;
    if (node < N_NODES) {
        int f = lane;
        float h = 0.f;
        if (f < NFP) {
            float ewf = ew[f], ebf = ebv[f];
            float acc = 0.f;
            int e0 = ptr[node], e1 = ptr[node + 1];
            for (int i = e0; i < e1; i++) {
                int s = srcs[i]; float wv = wsv[i];
                float m = x[s * NFP + f] + wv * ewf + ebf;
                acc += fmaxf(m, 0.f);
            }
            h = (1.f + epsp[0]) * x[node * NFP + f] + acc;
        }
        int o = lane & 15;
        float tv = b1[o];
        #pragma unroll
        for (int ff = 0; ff < NFP; ff++) tv += __shfl(h, ff) * W1[ff * DIM + o];
        tv = fmaxf(tv, 0.f);
        float zv = b2[o];
        #pragma unroll
        for (int ff = 0; ff < DIM; ff++) zv += __shfl(tv, ff) * W2[ff * DIM + o];
        zv = fmaxf(zv, 0.f);
        if (lane < DIM) {
            z[node * DIM + o] = zv;
            atomicAdd(&s_sum[o], zv);
            atomicAdd(&s_sq[o], zv * zv);
        }
    }
    __syncthreads();
    if (t < DIM) { atomicAdd(&bnstat[t], s_sum[t]); atomicAdd(&bnstat[DIM + t], s_sq[t]); }
}

// ---------------- GINE layers 2-5 (16 -> 16), wave per node ----------------
__global__ void __launch_bounds__(256) k_gine16(
    const float* __restrict__ x, const int* __restrict__ ptr,
    const int* __restrict__ srcs, const float* __restrict__ wsv,
    const float* __restrict__ ew, const float* __restrict__ ebv,
    const float* __restrict__ epsp,
    const float* __restrict__ W1, const float* __restrict__ b1,
    const float* __restrict__ W2, const float* __restrict__ b2,
    float* __restrict__ z, float* __restrict__ bnstat) {
    __shared__ float s_sum[DIM], s_sq[DIM];
    int t = threadIdx.x;
    if (t < DIM) { s_sum[t] = 0.f; s_sq[t] = 0.f; }
    __syncthreads();
    int wave = t >> 6, lane = t & 63;
    int node = blockIdx.x * 4 + wave;
    if (node < N_NODES) {
        int e4 = lane >> 4, f = lane & 15;
        float ewf = ew[f], ebf = ebv[f];
        float acc = 0.f;
        int e0 = ptr[node], e1 = ptr[node + 1];
        for (int i = e0 + e4; i < e1; i += 4) {
            int s = srcs[i]; float wv = wsv[i];
            float m = x[s * DIM + f] + wv * ewf + ebf;
            acc += fmaxf(m, 0.f);
        }
        acc += __shfl_xor(acc, 16);
        acc += __shfl_xor(acc, 32);
        float h = (1.f + epsp[0]) * x[node * DIM + f] + acc;
        float tv = b1[f];
        #pragma unroll
        for (int ff = 0; ff < DIM; ff++) tv += __shfl(h, ff) * W1[ff * DIM + f];
        tv = fmaxf(tv, 0.f);
        float zv = b2[f];
        #pragma unroll
        for (int ff = 0; ff < DIM; ff++) zv += __shfl(tv, ff) * W2[ff * DIM + f];
        zv = fmaxf(zv, 0.f);
        if (lane < DIM) {
            z[node * DIM + f] = zv;
            atomicAdd(&s_sum[f], zv);
            atomicAdd(&s_sq[f], zv * zv);
        }
    }
    __syncthreads();
    if (t < DIM) { atomicAdd(&bnstat[t], s_sum[t]); atomicAdd(&bnstat[DIM + t], s_sq[t]); }
}

// ---------------- BN normalize ----------------
__global__ void k_norm(const float* __restrict__ z, float* __restrict__ x,
                       const float* __restrict__ bnstat, const float* __restrict__ gamma,
                       const float* __restrict__ beta) {
    int i = blockIdx.x * blockDim.x + threadIdx.x;
    int base = i * 4;
    if (base >= N_NODES * DIM) return;
    float4 zv = *(const float4*)(z + base);
    float zz[4] = {zv.x, zv.y, zv.z, zv.w};
    float out[4];
    int f0 = base & 15;
    const float invn = 1.f / (float)N_NODES;
    #pragma unroll
    for (int j = 0; j < 4; j++) {
        int f = f0 + j;
        float mu = bnstat[f] * invn;
        float var = bnstat[DIM + f] * invn - mu * mu;
        float sc = gamma[f] * rsqrtf(var + BN_EPSV);
        float sh = beta[f] - mu * sc;
        out[j] = zz[j] * sc + sh;
    }
    *(float4*)(x + base) = make_float4(out[0], out[1], out[2], out[3]);
}

// ---------------- hierarchical pooling (batch is sorted) ----------------
__global__ void __launch_bounds__(256) k_pool(const float* __restrict__ x,
                                              const int* __restrict__ batch,
                                              float* __restrict__ gsum,
                                              float* __restrict__ gcnt) {
    __shared__ float lsum[BGR * DIM];
    __shared__ float lcnt[BGR];
    int t = threadIdx.x;
    for (int j = t; j < BGR * DIM; j += 256) lsum[j] = 0.f;
    if (t < BGR) lcnt[t] = 0.f;
    __syncthreads();
    int f = t & 15, r = t >> 4;
    int start = blockIdx.x * POOL_CHUNK;
    float acc = 0.f, cacc = 0.f;
    int cur = -1;
    for (int i = 0; i < POOL_CHUNK / 16; i++) {
        int n = start + r + i * 16;
        if (n >= N_NODES) break;
        int b = batch[n];
        if (b != cur) {
            if (cur >= 0) {
                atomicAdd(&lsum[cur * DIM + f], acc);
                if (f == 0) atomicAdd(&lcnt[cur], cacc);
            }
            cur = b; acc = 0.f; cacc = 0.f;
        }
        acc += x[n * DIM + f];
        cacc += 1.f;
    }
    if (cur >= 0) {
        atomicAdd(&lsum[cur * DIM + f], acc);
        if (f == 0) atomicAdd(&lcnt[cur], cacc);
    }
    __syncthreads();
    for (int j = t; j < BGR * DIM; j += 256) {
        float v = lsum[j];
        if (v != 0.f) atomicAdd(&gsum[j], v);
    }
    if (t < BGR) {
        float v = lcnt[t];
        if (v != 0.f) atomicAdd(&gcnt[t], v);
    }
}

__global__ void k_xp(const float* __restrict__ gsum, const float* __restrict__ gcnt,
                     const float* __restrict__ w, const float* __restrict__ bias,
                     float* __restrict__ out) {
    int b = blockIdx.x;
    int e = threadIdx.x;
    float inv = 1.f / fmaxf(gcnt[b], 1.f);
    float acc = bias[e];
    #pragma unroll
    for (int f = 0; f < DIM; f++) acc += gsum[b * DIM + f] * inv * w[f * EMB + e];
    out[b * EMB + e] = fmaxf(acc, 0.f);
}

// ---------------- RNA: token-bucketed conv weights ----------------
__global__ void __launch_bounds__(256) k_wg(const int* __restrict__ tok,
                                            const float* __restrict__ cw,
                                            float* __restrict__ W) {
    int b = blockIdx.x;
    int t = threadIdx.x;  // 256 = 32 o x 8 k
    int o = t >> 3, k = t & 7;
    __shared__ int tk[256];
    float a0 = 0, a1 = 0, a2 = 0, a3 = 0, a4 = 0;
    const float* cwp = cw + o * (MAXLEN * KS) + k;
    for (int l0 = 0; l0 < MAXLEN; l0 += 256) {
        int lim = MAXLEN - l0; if (lim > 256) lim = 256;
        __syncthreads();
        if (t < lim) tk[t] = tok[b * MAXLEN + l0 + t];
        __syncthreads();
        for (int j = 0; j < lim; j++) {
            int v = tk[j];
            float c = cwp[(l0 + j) * KS];
            a0 += (v == 0) ? c : 0.f;
            a1 += (v == 1) ? c : 0.f;
            a2 += (v == 2) ? c : 0.f;
            a3 += (v == 3) ? c : 0.f;
            a4 += (v == 4) ? c : 0.f;
        }
    }
    float* Wp = W + ((b * NF + o) * 5) * KS + k;
    Wp[0 * KS] = a0; Wp[1 * KS] = a1; Wp[2 * KS] = a2; Wp[3 * KS] = a3; Wp[4 * KS] = a4;
}

__global__ void __launch_bounds__(128) k_wl(const int* __restrict__ tok,
                                            const float* __restrict__ cw,
                                            float* __restrict__ W) {
    int b = blockIdx.x;
    int half = blockIdx.y;
    int t = threadIdx.x;  // 128 = 16 o x 8 k
    int o = (t >> 3) + half * 16, k = t & 7;
    __shared__ float acc[128][65];
    __shared__ int tk[256];
    for (int v = 0; v < 65; v++) acc[t][v] = 0.f;
    const float* cwp = cw + o * (LOCLEN * KS) + k;
    for (int l0 = 0; l0 < LOCLEN; l0 += 256) {
        int lim = LOCLEN - l0; if (lim > 256) lim = 256;
        __syncthreads();
        for (int j = t; j < lim; j += 128) tk[j] = tok[b * LOCLEN + l0 + j];
        __syncthreads();
        for (int j = 0; j < lim; j++) {
            int v = tk[j];
            acc[t][v] += cwp[(l0 + j) * KS];
        }
    }
    float* Wp = W + ((b * NF + o) * 65) * KS + k;
    for (int v = 0; v < 65; v++) Wp[v * KS] = acc[t][v];
}

__global__ void k_y(const float* __restrict__ Wg, const float* __restrict__ Wl,
                    const float* __restrict__ emb1, const float* __restrict__ emb2,
                    const float* __restrict__ cb1, const float* __restrict__ cb2,
                    float* __restrict__ yg, float* __restrict__ yl) {
    int which = blockIdx.y;
    int bo = blockIdx.x;
    int b = bo >> 5, o = bo & 31;
    int t = threadIdx.x;  // 128
    const float* W = which ? Wl : Wg;
    const float* emb = which ? emb2 : emb1;
    const float* cb = which ? cb2 : cb1;
    float* y = which ? yl : yg;
    int V = which ? 65 : 5;
    __shared__ float Wsh[65 * KS];
    const float* Wrow = W + (b * NF + o) * V * KS;
    for (int j = t; j < V * KS; j += 128) Wsh[j] = Wrow[j];
    __syncthreads();
    if (t < OUTT) {
        float acc = cb[o];
        for (int v = 0; v < V; v++) {
            const float* ep = emb + v * EMB + t;
            #pragma unroll
            for (int k = 0; k < KS; k++) acc += Wsh[v * KS + k] * ep[k];
        }
        y[(b * NF + o) * OUTT + t] = acc;
    }
}

__global__ void k_fc(const float* __restrict__ yg, const float* __restrict__ yl,
                     const float* __restrict__ w, const float* __restrict__ bias,
                     float* __restrict__ xrg, float* __restrict__ xrl) {
    int b = blockIdx.x;
    int which = blockIdx.y;
    const float* y = which ? yl : yg;
    float* xr = which ? xrl : xrg;
    int e = threadIdx.x;  // 128
    __shared__ float ych[128];
    float acc = bias[e];
    for (int j0 = 0; j0 < FC_IN; j0 += 128) {
        __syncthreads();
        int lim = FC_IN - j0; if (lim > 128) lim = 128;
        if (e < lim) ych[e] = y[b * FC_IN + j0 + e];
        __syncthreads();
        for (int jj = 0; jj < lim; jj++) acc += ych[jj] * w[(j0 + jj) * EMB + e];
    }
    xr[b * EMB + e] = acc;
}

__global__ void k_comb(const float* __restrict__ xrg, const float* __restrict__ xrl,
                       float* __restrict__ out) {
    int i = blockIdx.x * blockDim.x + threadIdx.x;
    if (i < BGR * EMB) out[i] = 0.5f * (xrg[i] + xrl[i]);
}

extern "C" void kernel_launch(void* const* d_in, const int* in_sizes, int n_in,
                              void* d_out, int out_size, void* d_ws, size_t ws_size,
                              hipStream_t stream) {
    const float* pro_x = (const float*)d_in[0];
    const int* eidx = (const int*)d_in[1];
    const int* esrc = eidx;
    const int* edst = eidx + N_EDGES;
    const float* pw = (const float*)d_in[2];
    const int* batch = (const int*)d_in[3];
    const int* rg = (const int*)d_in[4];
    const int* rl = (const int*)d_in[5];
    const float* g1_w1 = (const float*)d_in[6];
    const float* g1_b1 = (const float*)d_in[7];
    const float* g1_w2 = (const float*)d_in[8];
    const float* g1_b2 = (const float*)d_in[9];
    const float* g1_ew = (const float*)d_in[10];
    const float* g1_eb = (const float*)d_in[11];
    const float* g1_eps = (const float*)d_in[12];
    const float* g_w1 = (const float*)d_in[13];
    const float* g_b1 = (const float*)d_in[14];
    const float* g_w2 = (const float*)d_in[15];
    const float* g_b2 = (const float*)d_in[16];
    const float* g_ew = (const float*)d_in[17];
    const float* g_eb = (const float*)d_in[18];
    const float* g_eps = (const float*)d_in[19];
    const float* bn_gamma = (const float*)d_in[20];
    const float* bn_beta = (const float*)d_in[21];
    const float* fc1_xp_w = (const float*)d_in[22];
    const float* fc1_xp_b = (const float*)d_in[23];
    const float* emb1 = (const float*)d_in[24];
    const float* emb2 = (const float*)d_in[25];
    const float* convr1_w = (const float*)d_in[26];
    const float* convr1_b = (const float*)d_in[27];
    const float* convr2_w = (const float*)d_in[28];
    const float* convr2_b = (const float*)d_in[29];
    const float* fcxr_w = (const float*)d_in[30];
    const float* fcxr_b = (const float*)d_in[31];
    float* out = (float*)d_out;

    float* wsf = (float*)d_ws;
    int* ptr     = (int*)wsf;          wsf += 100096;
    int* cnt     = (int*)wsf;          wsf += 100096;
    int* cursor  = (int*)wsf;          wsf += 100096;
    int* src_s   = (int*)wsf;          wsf += N_EDGES;
    float* w_s   = wsf;                wsf += N_EDGES;
    float* xA    = wsf;                wsf += N_NODES * DIM;
    float* xB    = wsf;                wsf += N_NODES * DIM;
    float* stats = wsf;                wsf += 1280;
    float* Wg    = wsf;                wsf += BGR * NF * 5 * KS;
    float* Wl    = wsf;                wsf += BGR * NF * 65 * KS;
    float* yg    = wsf;                wsf += BGR * NF * OUTT;
    float* yl    = wsf;                wsf += BGR * NF * OUTT;
    float* xrg   = wsf;                wsf += BGR * EMB;
    float* xrl   = wsf;                wsf += BGR * EMB;
    float* gsum   = stats;
    float* gcnt   = stats + 1024;
    float* bnstat = stats + 1088;

    hipMemsetAsync(cnt, 0, N_NODES * sizeof(int), stream);
    hipMemsetAsync(stats, 0, 1280 * sizeof(float), stream);

    // CSR build
    k_count<<<N_EDGES / 256, 256, 0, stream>>>(edst, cnt);
    k_scan<<<1, 1024, 0, stream>>>(cnt, ptr, cursor);
    k_scatter<<<N_EDGES / 256, 256, 0, stream>>>(esrc, edst, pw, cursor, src_s, w_s);

    // RNA branch
    k_wg<<<BGR, 256, 0, stream>>>(rg, convr1_w, Wg);
    k_wl<<<dim3(BGR, 2), 128, 0, stream>>>(rl, convr2_w, Wl);
    k_y<<<dim3(BGR * NF, 2), 128, 0, stream>>>(Wg, Wl, emb1, emb2, convr1_b, convr2_b, yg, yl);
    k_fc<<<dim3(BGR, 2), 128, 0, stream>>>(yg, yl, fcxr_w, fcxr_b, xrg, xrl);
    k_comb<<<(BGR * EMB + 255) / 256, 256, 0, stream>>>(xrg, xrl, out);

    // GNN stack
    int gblocks = (N_NODES + 3) / 4;
    int nblocks = (N_NODES * DIM / 4 + 255) / 256;
    k_gine1<<<gblocks, 256, 0, stream>>>(pro_x, ptr, src_s, w_s, g1_ew, g1_eb, g1_eps,
                                         g1_w1, g1_b1, g1_w2, g1_b2, xB, bnstat);
    k_norm<<<nblocks, 256, 0, stream>>>(xB, xA, bnstat, bn_gamma, bn_beta);
    for (int i = 0; i < 4; i++) {
        k_gine16<<<gblocks, 256, 0, stream>>>(xA, ptr, src_s, w_s,
                                              g_ew + i * DIM, g_eb + i * DIM, g_eps + i,
                                              g_w1 + i * DIM * DIM, g_b1 + i * DIM,
                                              g_w2 + i * DIM * DIM, g_b2 + i * DIM,
                                              xB, bnstat + (i + 1) * 32);
        k_norm<<<nblocks, 256, 0, stream>>>(xB, xA, bnstat + (i + 1) * 32,
                                            bn_gamma + (i + 1) * DIM, bn_beta + (i + 1) * DIM);
    }
    k_pool<<<(N_NODES + POOL_CHUNK - 1) / POOL_CHUNK, 256, 0, stream>>>(xA, batch, gsum, gcnt);
    k_xp<<<BGR, EMB, 0, stream>>>(gsum, gcnt, fc1_xp_w, fc1_xp_b, out + BGR * EMB);
}

// Round 3
// 2797.563 us; speedup vs baseline: 1.4053x; 1.1452x over previous
//
#include <hip/hip_runtime.h>

#define N_NODES 100000
#define N_EDGES 3200000
#define BGR 64
#define DIM 16
#define NFP 33
#define EMB 128
#define MAXLEN 3000
#define LOCLEN 2998
#define NF 32
#define KS 8
#define OUTT 121
#define FC_IN 3872
#define BN_EPSV 1e-5f
#define POOL_CHUNK 2048

// ---------------- CSR build ----------------
__global__ void k_count(const int* __restrict__ dst, int* __restrict__ cnt) {
    int i = blockIdx.x * blockDim.x + threadIdx.x;
    if (i < N_EDGES) atomicAdd(&cnt[dst[i]], 1);
}

__global__ void k_scan(const int* __restrict__ cnt, int* __restrict__ ptr,
                       int* __restrict__ cursor) {
    __shared__ int part[1024];
    const int CH = (N_NODES + 1023) / 1024;  // 98
    int t = threadIdx.x;
    int base = t * CH;
    int s = 0;
    for (int i = 0; i < CH; i++) { int idx = base + i; if (idx < N_NODES) s += cnt[idx]; }
    part[t] = s;
    __syncthreads();
    for (int off = 1; off < 1024; off <<= 1) {
        int v = (t >= off) ? part[t - off] : 0;
        __syncthreads();
        part[t] += v;
        __syncthreads();
    }
    int run = (t == 0) ? 0 : part[t - 1];
    for (int i = 0; i < CH; i++) {
        int idx = base + i;
        if (idx < N_NODES) {
            int c = cnt[idx];
            ptr[idx] = run; cursor[idx] = run;
            run += c;
        }
    }
    if (t == 1023) ptr[N_NODES] = part[1023];
}

__global__ void k_scatter(const int* __restrict__ src, const int* __restrict__ dst,
                          const float* __restrict__ w, int* __restrict__ cursor,
                          int* __restrict__ src_s, float* __restrict__ w_s) {
    int i = blockIdx.x * blockDim.x + threadIdx.x;
    if (i < N_EDGES) {
        int d = dst[i];
        int p = atomicAdd(&cursor[d], 1);
        src_s[p] = src[i];
        w_s[p] = w[i];
    }
}

// ---------------- GINE layer 1 (33 -> 16): 8 edge slots x 8 feature-quads ----------------
__global__ void __launch_bounds__(256) k_gine1(
    const float* __restrict__ x, const int* __restrict__ ptr,
    const int* __restrict__ srcs, const float* __restrict__ wsv,
    const float* __restrict__ ew, const float* __restrict__ ebv,
    const float* __restrict__ epsp,
    const float* __restrict__ W1, const float* __restrict__ b1,
    const float* __restrict__ W2, const float* __restrict__ b2,
    float* __restrict__ z, float* __restrict__ bnstat) {
    __shared__ float s_sum[DIM], s_sq[DIM];
    int t = threadIdx.x;
    if (t < DIM) { s_sum[t] = 0.f; s_sq[t] = 0.f; }
    __syncthreads();
    int wave = t >> 6, lane = t & 63;
    int node = blockIdx.x * 4 + wave;
    if (node < N_NODES) {
        int e = lane >> 3, q = lane & 7;  // 8 edge slots, 8 quads (features 4q..4q+3)
        float4 ew4 = ((const float4*)ew)[q];
        float4 eb4 = ((const float4*)ebv)[q];
        float ew32 = ew[32], eb32 = ebv[32];
        float a0 = 0, a1 = 0, a2 = 0, a3 = 0, a32 = 0;
        int e0 = ptr[node], e1 = ptr[node + 1];
        for (int i = e0 + e; i < e1; i += 8) {
            int s = srcs[i]; float wv = wsv[i];
            const float* xr = x + s * NFP;
            float4 xv = *(const float4*)(xr + q * 4);
            a0 += fmaxf(xv.x + wv * ew4.x + eb4.x, 0.f);
            a1 += fmaxf(xv.y + wv * ew4.y + eb4.y, 0.f);
            a2 += fmaxf(xv.z + wv * ew4.z + eb4.z, 0.f);
            a3 += fmaxf(xv.w + wv * ew4.w + eb4.w, 0.f);
            if (q == 0) a32 += fmaxf(xr[32] + wv * ew32 + eb32, 0.f);
        }
        #pragma unroll
        for (int m = 8; m <= 32; m <<= 1) {
            a0 += __shfl_xor(a0, m); a1 += __shfl_xor(a1, m);
            a2 += __shfl_xor(a2, m); a3 += __shfl_xor(a3, m);
            a32 += __shfl_xor(a32, m);
        }
        float ep = 1.f + epsp[0];
        const float* xn = x + node * NFP;
        float4 xs = *(const float4*)(xn + q * 4);
        float hq[4] = {ep * xs.x + a0, ep * xs.y + a1, ep * xs.z + a2, ep * xs.w + a3};
        float h32 = ep * xn[32] + a32;
        int o = lane & 15;
        float tv = b1[o];
        #pragma unroll
        for (int ff = 0; ff < 32; ff++)
            tv += __shfl(hq[ff & 3], ff >> 2) * W1[ff * DIM + o];
        tv += __shfl(h32, 0) * W1[32 * DIM + o];
        tv = fmaxf(tv, 0.f);
        float zv = b2[o];
        #pragma unroll
        for (int ff = 0; ff < DIM; ff++) zv += __shfl(tv, ff) * W2[ff * DIM + o];
        zv = fmaxf(zv, 0.f);
        if (lane < DIM) {
            z[node * DIM + o] = zv;
            atomicAdd(&s_sum[o], zv);
            atomicAdd(&s_sq[o], zv * zv);
        }
    }
    __syncthreads();
    if (t < DIM) { atomicAdd(&bnstat[t], s_sum[t]); atomicAdd(&bnstat[DIM + t], s_sq[t]); }
}

// ---------------- GINE layers 2-5 (16 -> 16): 16 edge slots x 4 feature-quads ----------------
__global__ void __launch_bounds__(256) k_gine16(
    const float* __restrict__ x, const int* __restrict__ ptr,
    const int* __restrict__ srcs, const float* __restrict__ wsv,
    const float* __restrict__ ew, const float* __restrict__ ebv,
    const float* __restrict__ epsp,
    const float* __restrict__ W1, const float* __restrict__ b1,
    const float* __restrict__ W2, const float* __restrict__ b2,
    float* __restrict__ z, float* __restrict__ bnstat) {
    __shared__ float s_sum[DIM], s_sq[DIM];
    int t = threadIdx.x;
    if (t < DIM) { s_sum[t] = 0.f; s_sq[t] = 0.f; }
    __syncthreads();
    int wave = t >> 6, lane = t & 63;
    int node = blockIdx.x * 4 + wave;
    if (node < N_NODES) {
        int e = lane >> 2, q = lane & 3;  // 16 edge slots, 4 quads
        float4 ew4 = ((const float4*)ew)[q];
        float4 eb4 = ((const float4*)ebv)[q];
        float a0 = 0, a1 = 0, a2 = 0, a3 = 0;
        int e0 = ptr[node], e1 = ptr[node + 1];
        for (int i = e0 + e; i < e1; i += 16) {
            int s = srcs[i]; float wv = wsv[i];
            float4 xv = ((const float4*)(x + s * DIM))[q];
            a0 += fmaxf(xv.x + wv * ew4.x + eb4.x, 0.f);
            a1 += fmaxf(xv.y + wv * ew4.y + eb4.y, 0.f);
            a2 += fmaxf(xv.z + wv * ew4.z + eb4.z, 0.f);
            a3 += fmaxf(xv.w + wv * ew4.w + eb4.w, 0.f);
        }
        #pragma unroll
        for (int m = 4; m <= 32; m <<= 1) {
            a0 += __shfl_xor(a0, m); a1 += __shfl_xor(a1, m);
            a2 += __shfl_xor(a2, m); a3 += __shfl_xor(a3, m);
        }
        float ep = 1.f + epsp[0];
        float4 xs = ((const float4*)(x + node * DIM))[q];
        float hq[4] = {ep * xs.x + a0, ep * xs.y + a1, ep * xs.z + a2, ep * xs.w + a3};
        int f = lane & 15;
        float tv = b1[f];
        #pragma unroll
        for (int ff = 0; ff < DIM; ff++)
            tv += __shfl(hq[ff & 3], ff >> 2) * W1[ff * DIM + f];
        tv = fmaxf(tv, 0.f);
        float zv = b2[f];
        #pragma unroll
        for (int ff = 0; ff < DIM; ff++) zv += __shfl(tv, ff) * W2[ff * DIM + f];
        zv = fmaxf(zv, 0.f);
        if (lane < DIM) {
            z[node * DIM + f] = zv;
            atomicAdd(&s_sum[f], zv);
            atomicAdd(&s_sq[f], zv * zv);
        }
    }
    __syncthreads();
    if (t < DIM) { atomicAdd(&bnstat[t], s_sum[t]); atomicAdd(&bnstat[DIM + t], s_sq[t]); }
}

// ---------------- BN normalize ----------------
__global__ void k_norm(const float* __restrict__ z, float* __restrict__ x,
                       const float* __restrict__ bnstat, const float* __restrict__ gamma,
                       const float* __restrict__ beta) {
    int i = blockIdx.x * blockDim.x + threadIdx.x;
    int base = i * 4;
    if (base >= N_NODES * DIM) return;
    float4 zv = *(const float4*)(z + base);
    float zz[4] = {zv.x, zv.y, zv.z, zv.w};
    float out[4];
    int f0 = base & 15;
    const float invn = 1.f / (float)N_NODES;
    #pragma unroll
    for (int j = 0; j < 4; j++) {
        int f = f0 + j;
        float mu = bnstat[f] * invn;
        float var = bnstat[DIM + f] * invn - mu * mu;
        float sc = gamma[f] * rsqrtf(var + BN_EPSV);
        float sh = beta[f] - mu * sc;
        out[j] = zz[j] * sc + sh;
    }
    *(float4*)(x + base) = make_float4(out[0], out[1], out[2], out[3]);
}

// ---------------- hierarchical pooling (batch is sorted) ----------------
__global__ void __launch_bounds__(256) k_pool(const float* __restrict__ x,
                                              const int* __restrict__ batch,
                                              float* __restrict__ gsum,
                                              float* __restrict__ gcnt) {
    __shared__ float lsum[BGR * DIM];
    __shared__ float lcnt[BGR];
    int t = threadIdx.x;
    for (int j = t; j < BGR * DIM; j += 256) lsum[j] = 0.f;
    if (t < BGR) lcnt[t] = 0.f;
    __syncthreads();
    int f = t & 15, r = t >> 4;
    int start = blockIdx.x * POOL_CHUNK;
    float acc = 0.f, cacc = 0.f;
    int cur = -1;
    for (int i = 0; i < POOL_CHUNK / 16; i++) {
        int n = start + r + i * 16;
        if (n >= N_NODES) break;
        int b = batch[n];
        if (b != cur) {
            if (cur >= 0) {
                atomicAdd(&lsum[cur * DIM + f], acc);
                if (f == 0) atomicAdd(&lcnt[cur], cacc);
            }
            cur = b; acc = 0.f; cacc = 0.f;
        }
        acc += x[n * DIM + f];
        cacc += 1.f;
    }
    if (cur >= 0) {
        atomicAdd(&lsum[cur * DIM + f], acc);
        if (f == 0) atomicAdd(&lcnt[cur], cacc);
    }
    __syncthreads();
    for (int j = t; j < BGR * DIM; j += 256) {
        float v = lsum[j];
        if (v != 0.f) atomicAdd(&gsum[j], v);
    }
    if (t < BGR) {
        float v = lcnt[t];
        if (v != 0.f) atomicAdd(&gcnt[t], v);
    }
}

__global__ void k_xp(const float* __restrict__ gsum, const float* __restrict__ gcnt,
                     const float* __restrict__ w, const float* __restrict__ bias,
                     float* __restrict__ out) {
    int b = blockIdx.x;
    int e = threadIdx.x;
    float inv = 1.f / fmaxf(gcnt[b], 1.f);
    float acc = bias[e];
    #pragma unroll
    for (int f = 0; f < DIM; f++) acc += gsum[b * DIM + f] * inv * w[f * EMB + e];
    out[b * EMB + e] = fmaxf(acc, 0.f);
}

// ---------------- RNA: bucket tokens by value, then gather-sum ----------------
__global__ void __launch_bounds__(256) k_bucket(const int* __restrict__ tok, int L, int V,
                                                int* __restrict__ blist,
                                                int* __restrict__ bptr) {
    __shared__ int hist[65];
    __shared__ int cursor[65];
    int b = blockIdx.x, t = threadIdx.x;
    if (t < V) hist[t] = 0;
    __syncthreads();
    for (int l = t; l < L; l += 256) atomicAdd(&hist[tok[b * L + l]], 1);
    __syncthreads();
    if (t == 0) {
        int run = 0;
        for (int v = 0; v < V; v++) {
            cursor[v] = run;
            bptr[b * (V + 1) + v] = run;
            run += hist[v];
        }
        bptr[b * (V + 1) + V] = run;
    }
    __syncthreads();
    for (int l = t; l < L; l += 256) {
        int v = tok[b * L + l];
        int p = atomicAdd(&cursor[v], 1);
        blist[b * L + p] = l;
    }
}

// W[b,o,v,k] = sum_{l in bucket(b,v)} cw[o,l,k]; one thread per (o,k), no atomics
__global__ void __launch_bounds__(256) k_wsum(const int* __restrict__ blist,
                                              const int* __restrict__ bptr,
                                              const float* __restrict__ cw,
                                              float* __restrict__ W, int L, int V) {
    int b = blockIdx.x, v = blockIdx.y;
    int t = threadIdx.x, o = t >> 3, k = t & 7;
    int s = bptr[b * (V + 1) + v], e = bptr[b * (V + 1) + v + 1];
    __shared__ int tk[256];
    const float* cwp = cw + o * (L * KS) + k;
    float acc = 0.f;
    for (int j0 = s; j0 < e; j0 += 256) {
        int lim = e - j0; if (lim > 256) lim = 256;
        __syncthreads();
        if (t < lim) tk[t] = blist[b * L + j0 + t];
        __syncthreads();
        for (int j = 0; j < lim; j++) acc += cwp[tk[j] * KS];
    }
    W[((b * NF + o) * V + v) * KS + k] = acc;
}

__global__ void k_y(const float* __restrict__ Wg, const float* __restrict__ Wl,
                    const float* __restrict__ emb1, const float* __restrict__ emb2,
                    const float* __restrict__ cb1, const float* __restrict__ cb2,
                    float* __restrict__ yg, float* __restrict__ yl) {
    int which = blockIdx.y;
    int bo = blockIdx.x;
    int b = bo >> 5, o = bo & 31;
    int t = threadIdx.x;  // 128
    const float* W = which ? Wl : Wg;
    const float* emb = which ? emb2 : emb1;
    const float* cb = which ? cb2 : cb1;
    float* y = which ? yl : yg;
    int V = which ? 65 : 5;
    __shared__ float Wsh[65 * KS];
    const float* Wrow = W + (b * NF + o) * V * KS;
    for (int j = t; j < V * KS; j += 128) Wsh[j] = Wrow[j];
    __syncthreads();
    if (t < OUTT) {
        float acc = cb[o];
        for (int v = 0; v < V; v++) {
            const float* ep = emb + v * EMB + t;
            #pragma unroll
            for (int k = 0; k < KS; k++) acc += Wsh[v * KS + k] * ep[k];
        }
        y[(b * NF + o) * OUTT + t] = acc;
    }
}

__global__ void k_fc(const float* __restrict__ yg, const float* __restrict__ yl,
                     const float* __restrict__ w, const float* __restrict__ bias,
                     float* __restrict__ xrg, float* __restrict__ xrl) {
    int b = blockIdx.x;
    int which = blockIdx.y;
    const float* y = which ? yl : yg;
    float* xr = which ? xrl : xrg;
    int e = threadIdx.x;  // 128
    __shared__ float ych[128];
    float acc = bias[e];
    for (int j0 = 0; j0 < FC_IN; j0 += 128) {
        __syncthreads();
        int lim = FC_IN - j0; if (lim > 128) lim = 128;
        if (e < lim) ych[e] = y[b * FC_IN + j0 + e];
        __syncthreads();
        for (int jj = 0; jj < lim; jj++) acc += ych[jj] * w[(j0 + jj) * EMB + e];
    }
    xr[b * EMB + e] = acc;
}

__global__ void k_comb(const float* __restrict__ xrg, const float* __restrict__ xrl,
                       float* __restrict__ out) {
    int i = blockIdx.x * blockDim.x + threadIdx.x;
    if (i < BGR * EMB) out[i] = 0.5f * (xrg[i] + xrl[i]);
}

extern "C" void kernel_launch(void* const* d_in, const int* in_sizes, int n_in,
                              void* d_out, int out_size, void* d_ws, size_t ws_size,
                              hipStream_t stream) {
    const float* pro_x = (const float*)d_in[0];
    const int* eidx = (const int*)d_in[1];
    const int* esrc = eidx;
    const int* edst = eidx + N_EDGES;
    const float* pw = (const float*)d_in[2];
    const int* batch = (const int*)d_in[3];
    const int* rg = (const int*)d_in[4];
    const int* rl = (const int*)d_in[5];
    const float* g1_w1 = (const float*)d_in[6];
    const float* g1_b1 = (const float*)d_in[7];
    const float* g1_w2 = (const float*)d_in[8];
    const float* g1_b2 = (const float*)d_in[9];
    const float* g1_ew = (const float*)d_in[10];
    const float* g1_eb = (const float*)d_in[11];
    const float* g1_eps = (const float*)d_in[12];
    const float* g_w1 = (const float*)d_in[13];
    const float* g_b1 = (const float*)d_in[14];
    const float* g_w2 = (const float*)d_in[15];
    const float* g_b2 = (const float*)d_in[16];
    const float* g_ew = (const float*)d_in[17];
    const float* g_eb = (const float*)d_in[18];
    const float* g_eps = (const float*)d_in[19];
    const float* bn_gamma = (const float*)d_in[20];
    const float* bn_beta = (const float*)d_in[21];
    const float* fc1_xp_w = (const float*)d_in[22];
    const float* fc1_xp_b = (const float*)d_in[23];
    const float* emb1 = (const float*)d_in[24];
    const float* emb2 = (const float*)d_in[25];
    const float* convr1_w = (const float*)d_in[26];
    const float* convr1_b = (const float*)d_in[27];
    const float* convr2_w = (const float*)d_in[28];
    const float* convr2_b = (const float*)d_in[29];
    const float* fcxr_w = (const float*)d_in[30];
    const float* fcxr_b = (const float*)d_in[31];
    float* out = (float*)d_out;

    float* wsf = (float*)d_ws;
    int* ptr     = (int*)wsf;          wsf += 100096;
    int* cnt     = (int*)wsf;          wsf += 100096;
    int* cursor  = (int*)wsf;          wsf += 100096;
    int* src_s   = (int*)wsf;          wsf += N_EDGES;
    float* w_s   = wsf;                wsf += N_EDGES;
    float* xA    = wsf;                wsf += N_NODES * DIM;
    float* xB    = wsf;                wsf += N_NODES * DIM;
    float* stats = wsf;                wsf += 1280;
    float* Wg    = wsf;                wsf += BGR * NF * 5 * KS;
    float* Wl    = wsf;                wsf += BGR * NF * 65 * KS;
    float* yg    = wsf;                wsf += BGR * NF * OUTT;
    float* yl    = wsf;                wsf += BGR * NF * OUTT;
    float* xrg   = wsf;                wsf += BGR * EMB;
    float* xrl   = wsf;                wsf += BGR * EMB;
    int* blg     = (int*)wsf;          wsf += BGR * MAXLEN;
    int* bll     = (int*)wsf;          wsf += BGR * LOCLEN;
    int* bpg     = (int*)wsf;          wsf += BGR * 6;
    int* bpl     = (int*)wsf;          wsf += BGR * 66;
    float* gsum   = stats;
    float* gcnt   = stats + 1024;
    float* bnstat = stats + 1088;

    hipMemsetAsync(cnt, 0, N_NODES * sizeof(int), stream);
    hipMemsetAsync(stats, 0, 1280 * sizeof(float), stream);

    // CSR build
    k_count<<<N_EDGES / 256, 256, 0, stream>>>(edst, cnt);
    k_scan<<<1, 1024, 0, stream>>>(cnt, ptr, cursor);
    k_scatter<<<N_EDGES / 256, 256, 0, stream>>>(esrc, edst, pw, cursor, src_s, w_s);

    // RNA branch
    k_bucket<<<BGR, 256, 0, stream>>>(rg, MAXLEN, 5, blg, bpg);
    k_bucket<<<BGR, 256, 0, stream>>>(rl, LOCLEN, 65, bll, bpl);
    k_wsum<<<dim3(BGR, 5), 256, 0, stream>>>(blg, bpg, convr1_w, Wg, MAXLEN, 5);
    k_wsum<<<dim3(BGR, 65), 256, 0, stream>>>(bll, bpl, convr2_w, Wl, LOCLEN, 65);
    k_y<<<dim3(BGR * NF, 2), 128, 0, stream>>>(Wg, Wl, emb1, emb2, convr1_b, convr2_b, yg, yl);
    k_fc<<<dim3(BGR, 2), 128, 0, stream>>>(yg, yl, fcxr_w, fcxr_b, xrg, xrl);
    k_comb<<<(BGR * EMB + 255) / 256, 256, 0, stream>>>(xrg, xrl, out);

    // GNN stack
    int gblocks = (N_NODES + 3) / 4;
    int nblocks = (N_NODES * DIM / 4 + 255) / 256;
    k_gine1<<<gblocks, 256, 0, stream>>>(pro_x, ptr, src_s, w_s, g1_ew, g1_eb, g1_eps,
                                         g1_w1, g1_b1, g1_w2, g1_b2, xB, bnstat);
    k_norm<<<nblocks, 256, 0, stream>>>(xB, xA, bnstat, bn_gamma, bn_beta);
    for (int i = 0; i < 4; i++) {
        k_gine16<<<gblocks, 256, 0, stream>>>(xA, ptr, src_s, w_s,
                                              g_ew + i * DIM, g_eb + i * DIM, g_eps + i,
                                              g_w1 + i * DIM * DIM, g_b1 + i * DIM,
                                              g_w2 + i * DIM * DIM, g_b2 + i * DIM,
                                              xB, bnstat + (i + 1) * 32);
        k_norm<<<nblocks, 256, 0, stream>>>(xB, xA, bnstat + (i + 1) * 32,
                                            bn_gamma + (i + 1) * DIM, bn_beta + (i + 1) * DIM);
    }
    k_pool<<<(N_NODES + POOL_CHUNK - 1) / POOL_CHUNK, 256, 0, stream>>>(xA, batch, gsum, gcnt);
    k_xp<<<BGR, EMB, 0, stream>>>(gsum, gcnt, fc1_xp_w, fc1_xp_b, out + BGR * EMB);
}

// Round 4
// 2725.131 us; speedup vs baseline: 1.4426x; 1.0266x over previous
//
#include <hip/hip_runtime.h>
#include <hip/hip_fp16.h>

#define N_NODES 100000
#define N_EDGES 3200000
#define BGR 64
#define DIM 16
#define NFP 33
#define ROW1 36   // padded half-row for pro_x (72B)
#define EMB 128
#define MAXLEN 3000
#define LOCLEN 2998
#define NF 32
#define KS 8
#define OUTT 121
#define FC_IN 3872
#define BN_EPSV 1e-5f
#define POOL_CHUNK 2048

// ---------------- CSR build ----------------
__global__ void k_count(const int* __restrict__ dst, int* __restrict__ cnt) {
    int i = blockIdx.x * blockDim.x + threadIdx.x;
    if (i < N_EDGES) atomicAdd(&cnt[dst[i]], 1);
}

__global__ void k_scan(const int* __restrict__ cnt, int* __restrict__ ptr,
                       int* __restrict__ cursor) {
    __shared__ int part[1024];
    const int CH = (N_NODES + 1023) / 1024;  // 98
    int t = threadIdx.x;
    int base = t * CH;
    int s = 0;
    for (int i = 0; i < CH; i++) { int idx = base + i; if (idx < N_NODES) s += cnt[idx]; }
    part[t] = s;
    __syncthreads();
    for (int off = 1; off < 1024; off <<= 1) {
        int v = (t >= off) ? part[t - off] : 0;
        __syncthreads();
        part[t] += v;
        __syncthreads();
    }
    int run = (t == 0) ? 0 : part[t - 1];
    for (int i = 0; i < CH; i++) {
        int idx = base + i;
        if (idx < N_NODES) {
            int c = cnt[idx];
            ptr[idx] = run; cursor[idx] = run;
            run += c;
        }
    }
    if (t == 1023) ptr[N_NODES] = part[1023];
}

__global__ void k_scatter(const int* __restrict__ src, const int* __restrict__ dst,
                          const float* __restrict__ w, int* __restrict__ cursor,
                          int* __restrict__ src_s, float* __restrict__ w_s) {
    int i = blockIdx.x * blockDim.x + threadIdx.x;
    if (i < N_EDGES) {
        int d = dst[i];
        int p = atomicAdd(&cursor[d], 1);
        src_s[p] = src[i];
        w_s[p] = w[i];
    }
}

// ---------------- fp16 conversion of pro_x: [N,33] fp32 -> [N,36] half ----------------
__global__ void k_half1(const float* __restrict__ x, __half* __restrict__ xh) {
    int i = blockIdx.x * blockDim.x + threadIdx.x;
    if (i < N_NODES * NFP) {
        int n = i / NFP, f = i - n * NFP;
        xh[n * ROW1 + f] = __float2half(x[i]);
    }
}

// ---------------- GINE layer 1 (33 -> 16), fp16 gather: 8 edge slots x 8 lanes ----------------
__global__ void __launch_bounds__(256) k_gine1(
    const __half* __restrict__ xh, const int* __restrict__ ptr,
    const int* __restrict__ srcs, const float* __restrict__ wsv,
    const float* __restrict__ ew, const float* __restrict__ ebv,
    const float* __restrict__ epsp,
    const float* __restrict__ W1, const float* __restrict__ b1,
    const float* __restrict__ W2, const float* __restrict__ b2,
    float* __restrict__ z, float* __restrict__ bnstat) {
    __shared__ float s_sum[DIM], s_sq[DIM];
    int t = threadIdx.x;
    if (t < DIM) { s_sum[t] = 0.f; s_sq[t] = 0.f; }
    __syncthreads();
    int wave = t >> 6, lane = t & 63;
    int node = blockIdx.x * 4 + wave;
    if (node < N_NODES) {
        int e = lane >> 3, q = lane & 7;  // 8 edge slots, lane q covers features 4q..4q+3
        float4 ew4 = ((const float4*)ew)[q];
        float4 eb4 = ((const float4*)ebv)[q];
        float ew32 = ew[32], eb32 = ebv[32];
        float a0 = 0, a1 = 0, a2 = 0, a3 = 0, a32 = 0;
        int e0 = ptr[node], e1 = ptr[node + 1];
        for (int i = e0 + e; i < e1; i += 8) {
            int s = srcs[i]; float wv = wsv[i];
            const __half* xr = xh + s * ROW1;
            uint2 raw = *(const uint2*)(xr + q * 4);
            __half2 p0 = *(__half2*)&raw.x;
            __half2 p1 = *(__half2*)&raw.y;
            float2 f01 = __half22float2(p0);
            float2 f23 = __half22float2(p1);
            a0 += fmaxf(f01.x + wv * ew4.x + eb4.x, 0.f);
            a1 += fmaxf(f01.y + wv * ew4.y + eb4.y, 0.f);
            a2 += fmaxf(f23.x + wv * ew4.z + eb4.z, 0.f);
            a3 += fmaxf(f23.y + wv * ew4.w + eb4.w, 0.f);
            if (q == 0) a32 += fmaxf(__half2float(xr[32]) + wv * ew32 + eb32, 0.f);
        }
        #pragma unroll
        for (int m = 8; m <= 32; m <<= 1) {
            a0 += __shfl_xor(a0, m); a1 += __shfl_xor(a1, m);
            a2 += __shfl_xor(a2, m); a3 += __shfl_xor(a3, m);
            a32 += __shfl_xor(a32, m);
        }
        float ep = 1.f + epsp[0];
        const __half* xn = xh + node * ROW1;
        uint2 sraw = *(const uint2*)(xn + q * 4);
        __half2 s0 = *(__half2*)&sraw.x;
        __half2 s1 = *(__half2*)&sraw.y;
        float2 sf01 = __half22float2(s0);
        float2 sf23 = __half22float2(s1);
        float hq[4] = {ep * sf01.x + a0, ep * sf01.y + a1,
                       ep * sf23.x + a2, ep * sf23.y + a3};
        float xn32 = (q == 0) ? __half2float(xn[32]) : 0.f;
        float h32 = ep * xn32 + a32;
        int o = lane & 15;
        float tv = b1[o];
        #pragma unroll
        for (int ff = 0; ff < 32; ff++)
            tv += __shfl(hq[ff & 3], ff >> 2) * W1[ff * DIM + o];
        tv += __shfl(h32, 0) * W1[32 * DIM + o];
        tv = fmaxf(tv, 0.f);
        float zv = b2[o];
        #pragma unroll
        for (int ff = 0; ff < DIM; ff++) zv += __shfl(tv, ff) * W2[ff * DIM + o];
        zv = fmaxf(zv, 0.f);
        if (lane < DIM) {
            z[node * DIM + o] = zv;
            atomicAdd(&s_sum[o], zv);
            atomicAdd(&s_sq[o], zv * zv);
        }
    }
    __syncthreads();
    if (t < DIM) { atomicAdd(&bnstat[t], s_sum[t]); atomicAdd(&bnstat[DIM + t], s_sq[t]); }
}

// ---------------- GINE layers 2-5 (16 -> 16), fp16 gather: 32 edge slots x 2 lanes ----------------
__global__ void __launch_bounds__(256) k_gine16(
    const __half* __restrict__ xh, const int* __restrict__ ptr,
    const int* __restrict__ srcs, const float* __restrict__ wsv,
    const float* __restrict__ ew, const float* __restrict__ ebv,
    const float* __restrict__ epsp,
    const float* __restrict__ W1, const float* __restrict__ b1,
    const float* __restrict__ W2, const float* __restrict__ b2,
    float* __restrict__ z, float* __restrict__ bnstat) {
    __shared__ float s_sum[DIM], s_sq[DIM];
    int t = threadIdx.x;
    if (t < DIM) { s_sum[t] = 0.f; s_sq[t] = 0.f; }
    __syncthreads();
    int wave = t >> 6, lane = t & 63;
    int node = blockIdx.x * 4 + wave;
    if (node < N_NODES) {
        int slot = lane >> 1, h = lane & 1;  // 32 edge slots, lane-half h covers features 8h..8h+7
        float4 ewlo = ((const float4*)ew)[h * 2];
        float4 ewhi = ((const float4*)ew)[h * 2 + 1];
        float4 eblo = ((const float4*)ebv)[h * 2];
        float4 ebhi = ((const float4*)ebv)[h * 2 + 1];
        float a[8] = {0, 0, 0, 0, 0, 0, 0, 0};
        int e0 = ptr[node], e1 = ptr[node + 1];
        for (int i = e0 + slot; i < e1; i += 32) {
            int s = srcs[i]; float wv = wsv[i];
            uint4 raw = *(const uint4*)(xh + s * DIM + h * 8);
            float2 f01 = __half22float2(*(__half2*)&raw.x);
            float2 f23 = __half22float2(*(__half2*)&raw.y);
            float2 f45 = __half22float2(*(__half2*)&raw.z);
            float2 f67 = __half22float2(*(__half2*)&raw.w);
            a[0] += fmaxf(f01.x + wv * ewlo.x + eblo.x, 0.f);
            a[1] += fmaxf(f01.y + wv * ewlo.y + eblo.y, 0.f);
            a[2] += fmaxf(f23.x + wv * ewlo.z + eblo.z, 0.f);
            a[3] += fmaxf(f23.y + wv * ewlo.w + eblo.w, 0.f);
            a[4] += fmaxf(f45.x + wv * ewhi.x + ebhi.x, 0.f);
            a[5] += fmaxf(f45.y + wv * ewhi.y + ebhi.y, 0.f);
            a[6] += fmaxf(f67.x + wv * ewhi.z + ebhi.z, 0.f);
            a[7] += fmaxf(f67.y + wv * ewhi.w + ebhi.w, 0.f);
        }
        #pragma unroll
        for (int m = 2; m <= 32; m <<= 1) {
            #pragma unroll
            for (int j = 0; j < 8; j++) a[j] += __shfl_xor(a[j], m);
        }
        float ep = 1.f + epsp[0];
        uint4 sraw = *(const uint4*)(xh + node * DIM + h * 8);
        float2 s01 = __half22float2(*(__half2*)&sraw.x);
        float2 s23 = __half22float2(*(__half2*)&sraw.y);
        float2 s45 = __half22float2(*(__half2*)&sraw.z);
        float2 s67 = __half22float2(*(__half2*)&sraw.w);
        float hq[8] = {ep * s01.x + a[0], ep * s01.y + a[1], ep * s23.x + a[2],
                       ep * s23.y + a[3], ep * s45.x + a[4], ep * s45.y + a[5],
                       ep * s67.x + a[6], ep * s67.y + a[7]};
        int f = lane & 15;
        float tv = b1[f];
        #pragma unroll
        for (int ff = 0; ff < DIM; ff++)
            tv += __shfl(hq[ff & 7], (ff >> 3) & 1) * W1[ff * DIM + f];
        tv = fmaxf(tv, 0.f);
        float zv = b2[f];
        #pragma unroll
        for (int ff = 0; ff < DIM; ff++) zv += __shfl(tv, ff) * W2[ff * DIM + f];
        zv = fmaxf(zv, 0.f);
        if (lane < DIM) {
            z[node * DIM + f] = zv;
            atomicAdd(&s_sum[f], zv);
            atomicAdd(&s_sq[f], zv * zv);
        }
    }
    __syncthreads();
    if (t < DIM) { atomicAdd(&bnstat[t], s_sum[t]); atomicAdd(&bnstat[DIM + t], s_sq[t]); }
}

// ---------------- BN normalize: fp32 z -> fp16 x ----------------
__global__ void k_norm(const float* __restrict__ z, __half* __restrict__ xh,
                       const float* __restrict__ bnstat, const float* __restrict__ gamma,
                       const float* __restrict__ beta) {
    int i = blockIdx.x * blockDim.x + threadIdx.x;
    int base = i * 4;
    if (base >= N_NODES * DIM) return;
    float4 zv = *(const float4*)(z + base);
    float zz[4] = {zv.x, zv.y, zv.z, zv.w};
    float out[4];
    int f0 = base & 15;
    const float invn = 1.f / (float)N_NODES;
    #pragma unroll
    for (int j = 0; j < 4; j++) {
        int f = f0 + j;
        float mu = bnstat[f] * invn;
        float var = bnstat[DIM + f] * invn - mu * mu;
        float sc = gamma[f] * rsqrtf(var + BN_EPSV);
        float sh = beta[f] - mu * sc;
        out[j] = zz[j] * sc + sh;
    }
    __half2* dst = (__half2*)(xh + base);
    dst[0] = __floats2half2_rn(out[0], out[1]);
    dst[1] = __floats2half2_rn(out[2], out[3]);
}

// ---------------- hierarchical pooling (batch is sorted), fp16 input ----------------
__global__ void __launch_bounds__(256) k_pool(const __half* __restrict__ xh,
                                              const int* __restrict__ batch,
                                              float* __restrict__ gsum,
                                              float* __restrict__ gcnt) {
    __shared__ float lsum[BGR * DIM];
    __shared__ float lcnt[BGR];
    int t = threadIdx.x;
    for (int j = t; j < BGR * DIM; j += 256) lsum[j] = 0.f;
    if (t < BGR) lcnt[t] = 0.f;
    __syncthreads();
    int f = t & 15, r = t >> 4;
    int start = blockIdx.x * POOL_CHUNK;
    float acc = 0.f, cacc = 0.f;
    int cur = -1;
    for (int i = 0; i < POOL_CHUNK / 16; i++) {
        int n = start + r + i * 16;
        if (n >= N_NODES) break;
        int b = batch[n];
        if (b != cur) {
            if (cur >= 0) {
                atomicAdd(&lsum[cur * DIM + f], acc);
                if (f == 0) atomicAdd(&lcnt[cur], cacc);
            }
            cur = b; acc = 0.f; cacc = 0.f;
        }
        acc += __half2float(xh[n * DIM + f]);
        cacc += 1.f;
    }
    if (cur >= 0) {
        atomicAdd(&lsum[cur * DIM + f], acc);
        if (f == 0) atomicAdd(&lcnt[cur], cacc);
    }
    __syncthreads();
    for (int j = t; j < BGR * DIM; j += 256) {
        float v = lsum[j];
        if (v != 0.f) atomicAdd(&gsum[j], v);
    }
    if (t < BGR) {
        float v = lcnt[t];
        if (v != 0.f) atomicAdd(&gcnt[t], v);
    }
}

__global__ void k_xp(const float* __restrict__ gsum, const float* __restrict__ gcnt,
                     const float* __restrict__ w, const float* __restrict__ bias,
                     float* __restrict__ out) {
    int b = blockIdx.x;
    int e = threadIdx.x;
    float inv = 1.f / fmaxf(gcnt[b], 1.f);
    float acc = bias[e];
    #pragma unroll
    for (int f = 0; f < DIM; f++) acc += gsum[b * DIM + f] * inv * w[f * EMB + e];
    out[b * EMB + e] = fmaxf(acc, 0.f);
}

// ---------------- RNA: bucket tokens by value, then gather-sum ----------------
__global__ void __launch_bounds__(256) k_bucket(const int* __restrict__ tok, int L, int V,
                                                int* __restrict__ blist,
                                                int* __restrict__ bptr) {
    __shared__ int hist[65];
    __shared__ int cursor[65];
    int b = blockIdx.x, t = threadIdx.x;
    if (t < V) hist[t] = 0;
    __syncthreads();
    for (int l = t; l < L; l += 256) atomicAdd(&hist[tok[b * L + l]], 1);
    __syncthreads();
    if (t == 0) {
        int run = 0;
        for (int v = 0; v < V; v++) {
            cursor[v] = run;
            bptr[b * (V + 1) + v] = run;
            run += hist[v];
        }
        bptr[b * (V + 1) + V] = run;
    }
    __syncthreads();
    for (int l = t; l < L; l += 256) {
        int v = tok[b * L + l];
        int p = atomicAdd(&cursor[v], 1);
        blist[b * L + p] = l;
    }
}

__global__ void __launch_bounds__(256) k_wsum(const int* __restrict__ blist,
                                              const int* __restrict__ bptr,
                                              const float* __restrict__ cw,
                                              float* __restrict__ W, int L, int V) {
    int b = blockIdx.x, v = blockIdx.y;
    int t = threadIdx.x, o = t >> 3, k = t & 7;
    int s = bptr[b * (V + 1) + v], e = bptr[b * (V + 1) + v + 1];
    __shared__ int tk[256];
    const float* cwp = cw + o * (L * KS) + k;
    float acc = 0.f;
    for (int j0 = s; j0 < e; j0 += 256) {
        int lim = e - j0; if (lim > 256) lim = 256;
        __syncthreads();
        if (t < lim) tk[t] = blist[b * L + j0 + t];
        __syncthreads();
        for (int j = 0; j < lim; j++) acc += cwp[tk[j] * KS];
    }
    W[((b * NF + o) * V + v) * KS + k] = acc;
}

__global__ void k_y(const float* __restrict__ Wg, const float* __restrict__ Wl,
                    const float* __restrict__ emb1, const float* __restrict__ emb2,
                    const float* __restrict__ cb1, const float* __restrict__ cb2,
                    float* __restrict__ yg, float* __restrict__ yl) {
    int which = blockIdx.y;
    int bo = blockIdx.x;
    int b = bo >> 5, o = bo & 31;
    int t = threadIdx.x;  // 128
    const float* W = which ? Wl : Wg;
    const float* emb = which ? emb2 : emb1;
    const float* cb = which ? cb2 : cb1;
    float* y = which ? yl : yg;
    int V = which ? 65 : 5;
    __shared__ float Wsh[65 * KS];
    const float* Wrow = W + (b * NF + o) * V * KS;
    for (int j = t; j < V * KS; j += 128) Wsh[j] = Wrow[j];
    __syncthreads();
    if (t < OUTT) {
        float acc = cb[o];
        for (int v = 0; v < V; v++) {
            const float* ep = emb + v * EMB + t;
            #pragma unroll
            for (int k = 0; k < KS; k++) acc += Wsh[v * KS + k] * ep[k];
        }
        y[(b * NF + o) * OUTT + t] = acc;
    }
}

__global__ void k_fc(const float* __restrict__ yg, const float* __restrict__ yl,
                     const float* __restrict__ w, const float* __restrict__ bias,
                     float* __restrict__ xrg, float* __restrict__ xrl) {
    int b = blockIdx.x;
    int which = blockIdx.y;
    const float* y = which ? yl : yg;
    float* xr = which ? xrl : xrg;
    int e = threadIdx.x;  // 128
    __shared__ float ych[128];
    float acc = bias[e];
    for (int j0 = 0; j0 < FC_IN; j0 += 128) {
        __syncthreads();
        int lim = FC_IN - j0; if (lim > 128) lim = 128;
        if (e < lim) ych[e] = y[b * FC_IN + j0 + e];
        __syncthreads();
        for (int jj = 0; jj < lim; jj++) acc += ych[jj] * w[(j0 + jj) * EMB + e];
    }
    xr[b * EMB + e] = acc;
}

__global__ void k_comb(const float* __restrict__ xrg, const float* __restrict__ xrl,
                       float* __restrict__ out) {
    int i = blockIdx.x * blockDim.x + threadIdx.x;
    if (i < BGR * EMB) out[i] = 0.5f * (xrg[i] + xrl[i]);
}

extern "C" void kernel_launch(void* const* d_in, const int* in_sizes, int n_in,
                              void* d_out, int out_size, void* d_ws, size_t ws_size,
                              hipStream_t stream) {
    const float* pro_x = (const float*)d_in[0];
    const int* eidx = (const int*)d_in[1];
    const int* esrc = eidx;
    const int* edst = eidx + N_EDGES;
    const float* pw = (const float*)d_in[2];
    const int* batch = (const int*)d_in[3];
    const int* rg = (const int*)d_in[4];
    const int* rl = (const int*)d_in[5];
    const float* g1_w1 = (const float*)d_in[6];
    const float* g1_b1 = (const float*)d_in[7];
    const float* g1_w2 = (const float*)d_in[8];
    const float* g1_b2 = (const float*)d_in[9];
    const float* g1_ew = (const float*)d_in[10];
    const float* g1_eb = (const float*)d_in[11];
    const float* g1_eps = (const float*)d_in[12];
    const float* g_w1 = (const float*)d_in[13];
    const float* g_b1 = (const float*)d_in[14];
    const float* g_w2 = (const float*)d_in[15];
    const float* g_b2 = (const float*)d_in[16];
    const float* g_ew = (const float*)d_in[17];
    const float* g_eb = (const float*)d_in[18];
    const float* g_eps = (const float*)d_in[19];
    const float* bn_gamma = (const float*)d_in[20];
    const float* bn_beta = (const float*)d_in[21];
    const float* fc1_xp_w = (const float*)d_in[22];
    const float* fc1_xp_b = (const float*)d_in[23];
    const float* emb1 = (const float*)d_in[24];
    const float* emb2 = (const float*)d_in[25];
    const float* convr1_w = (const float*)d_in[26];
    const float* convr1_b = (const float*)d_in[27];
    const float* convr2_w = (const float*)d_in[28];
    const float* convr2_b = (const float*)d_in[29];
    const float* fcxr_w = (const float*)d_in[30];
    const float* fcxr_b = (const float*)d_in[31];
    float* out = (float*)d_out;

    float* wsf = (float*)d_ws;
    int* ptr     = (int*)wsf;          wsf += 100096;
    int* cnt     = (int*)wsf;          wsf += 100096;
    int* cursor  = (int*)wsf;          wsf += 100096;
    int* src_s   = (int*)wsf;          wsf += N_EDGES;
    float* w_s   = wsf;                wsf += N_EDGES;
    float* z     = wsf;                wsf += N_NODES * DIM;          // fp32 gine out
    __half* xh   = (__half*)wsf;       wsf += N_NODES * DIM / 2;      // fp16 activations
    __half* xh1  = (__half*)wsf;       wsf += N_NODES * ROW1 / 2;     // fp16 pro_x (padded)
    float* stats = wsf;                wsf += 1280;
    float* Wg    = wsf;                wsf += BGR * NF * 5 * KS;
    float* Wl    = wsf;                wsf += BGR * NF * 65 * KS;
    float* yg    = wsf;                wsf += BGR * NF * OUTT;
    float* yl    = wsf;                wsf += BGR * NF * OUTT;
    float* xrg   = wsf;                wsf += BGR * EMB;
    float* xrl   = wsf;                wsf += BGR * EMB;
    int* blg     = (int*)wsf;          wsf += BGR * MAXLEN;
    int* bll     = (int*)wsf;          wsf += BGR * LOCLEN;
    int* bpg     = (int*)wsf;          wsf += BGR * 6;
    int* bpl     = (int*)wsf;          wsf += BGR * 66;
    float* gsum   = stats;
    float* gcnt   = stats + 1024;
    float* bnstat = stats + 1088;

    hipMemsetAsync(cnt, 0, N_NODES * sizeof(int), stream);
    hipMemsetAsync(stats, 0, 1280 * sizeof(float), stream);

    // CSR build
    k_count<<<N_EDGES / 256, 256, 0, stream>>>(edst, cnt);
    k_scan<<<1, 1024, 0, stream>>>(cnt, ptr, cursor);
    k_scatter<<<N_EDGES / 256, 256, 0, stream>>>(esrc, edst, pw, cursor, src_s, w_s);

    // pro_x -> fp16 padded rows
    k_half1<<<(N_NODES * NFP + 255) / 256, 256, 0, stream>>>(pro_x, xh1);

    // RNA branch
    k_bucket<<<BGR, 256, 0, stream>>>(rg, MAXLEN, 5, blg, bpg);
    k_bucket<<<BGR, 256, 0, stream>>>(rl, LOCLEN, 65, bll, bpl);
    k_wsum<<<dim3(BGR, 5), 256, 0, stream>>>(blg, bpg, convr1_w, Wg, MAXLEN, 5);
    k_wsum<<<dim3(BGR, 65), 256, 0, stream>>>(bll, bpl, convr2_w, Wl, LOCLEN, 65);
    k_y<<<dim3(BGR * NF, 2), 128, 0, stream>>>(Wg, Wl, emb1, emb2, convr1_b, convr2_b, yg, yl);
    k_fc<<<dim3(BGR, 2), 128, 0, stream>>>(yg, yl, fcxr_w, fcxr_b, xrg, xrl);
    k_comb<<<(BGR * EMB + 255) / 256, 256, 0, stream>>>(xrg, xrl, out);

    // GNN stack
    int gblocks = (N_NODES + 3) / 4;
    int nblocks = (N_NODES * DIM / 4 + 255) / 256;
    k_gine1<<<gblocks, 256, 0, stream>>>(xh1, ptr, src_s, w_s, g1_ew, g1_eb, g1_eps,
                                         g1_w1, g1_b1, g1_w2, g1_b2, z, bnstat);
    k_norm<<<nblocks, 256, 0, stream>>>(z, xh, bnstat, bn_gamma, bn_beta);
    for (int i = 0; i < 4; i++) {
        k_gine16<<<gblocks, 256, 0, stream>>>(xh, ptr, src_s, w_s,
                                              g_ew + i * DIM, g_eb + i * DIM, g_eps + i,
                                              g_w1 + i * DIM * DIM, g_b1 + i * DIM,
                                              g_w2 + i * DIM * DIM, g_b2 + i * DIM,
                                              z, bnstat + (i + 1) * 32);
        k_norm<<<nblocks, 256, 0, stream>>>(z, xh, bnstat + (i + 1) * 32,
                                            bn_gamma + (i + 1) * DIM, bn_beta + (i + 1) * DIM);
    }
    k_pool<<<(N_NODES + POOL_CHUNK - 1) / POOL_CHUNK, 256, 0, stream>>>(xh, batch, gsum, gcnt);
    k_xp<<<BGR, EMB, 0, stream>>>(gsum, gcnt, fc1_xp_w, fc1_xp_b, out + BGR * EMB);
}

// Round 5
// 1818.696 us; speedup vs baseline: 2.1616x; 1.4984x over previous
//
#include <hip/hip_runtime.h>
#include <hip/hip_fp16.h>

#define N_NODES 100000
#define N_EDGES 3200000
#define BGR 64
#define DIM 16
#define NFP 33
#define ROW1 36   // padded half-row for pro_x (72B)
#define EMB 128
#define MAXLEN 3000
#define LOCLEN 2998
#define NF 32
#define KS 8
#define OUTT 121
#define FC_IN 3872
#define BN_EPSV 1e-5f
#define POOL_CHUNK 2048
#define NQUAD 25000      // N_NODES / 4
#define GBLK 3125        // gine grid: each block handles 8 quads

// ---------------- CSR build ----------------
__global__ void k_count(const int* __restrict__ dst, int* __restrict__ cnt) {
    int i = blockIdx.x * blockDim.x + threadIdx.x;
    if (i < N_EDGES) atomicAdd(&cnt[dst[i]], 1);
}

__global__ void k_scan(const int* __restrict__ cnt, int* __restrict__ ptr,
                       int* __restrict__ cursor) {
    __shared__ int part[1024];
    const int CH = (N_NODES + 1023) / 1024;  // 98
    int t = threadIdx.x;
    int base = t * CH;
    int s = 0;
    for (int i = 0; i < CH; i++) { int idx = base + i; if (idx < N_NODES) s += cnt[idx]; }
    part[t] = s;
    __syncthreads();
    for (int off = 1; off < 1024; off <<= 1) {
        int v = (t >= off) ? part[t - off] : 0;
        __syncthreads();
        part[t] += v;
        __syncthreads();
    }
    int run = (t == 0) ? 0 : part[t - 1];
    for (int i = 0; i < CH; i++) {
        int idx = base + i;
        if (idx < N_NODES) {
            int c = cnt[idx];
            ptr[idx] = run; cursor[idx] = run;
            run += c;
        }
    }
    if (t == 1023) ptr[N_NODES] = part[1023];
}

__global__ void k_scatter(const int* __restrict__ src, const int* __restrict__ dst,
                          const float* __restrict__ w, int* __restrict__ cursor,
                          int* __restrict__ src_s, float* __restrict__ w_s) {
    int i = blockIdx.x * blockDim.x + threadIdx.x;
    if (i < N_EDGES) {
        int d = dst[i];
        int p = atomicAdd(&cursor[d], 1);
        src_s[p] = src[i];
        w_s[p] = w[i];
    }
}

// ---------------- fp16 conversion of pro_x ----------------
__global__ void k_half1(const float* __restrict__ x, __half* __restrict__ xh) {
    int i = blockIdx.x * blockDim.x + threadIdx.x;
    if (i < N_NODES * NFP) {
        int n = i / NFP, f = i - n * NFP;
        xh[n * ROW1 + f] = __float2half(x[i]);
    }
}

// ---------------- GINE layer 1 (33 -> 16): no global atomics, partial BN stats ----------------
__global__ void __launch_bounds__(256) k_gine1(
    const __half* __restrict__ xh, const int* __restrict__ ptr,
    const int* __restrict__ srcs, const float* __restrict__ wsv,
    const float* __restrict__ ew, const float* __restrict__ ebv,
    const float* __restrict__ epsp,
    const float* __restrict__ W1, const float* __restrict__ b1,
    const float* __restrict__ W2, const float* __restrict__ b2,
    float* __restrict__ z, float* __restrict__ part) {
    __shared__ float s_acc[32];
    int t = threadIdx.x;
    int wave = t >> 6, lane = t & 63;
    int e = lane >> 3, q = lane & 7;
    float4 ew4 = ((const float4*)ew)[q];
    float4 eb4 = ((const float4*)ebv)[q];
    float ew32 = ew[32], eb32 = ebv[32];
    float ep = 1.f + epsp[0];
    float rs = 0.f, rq = 0.f;
    for (int quad = blockIdx.x; quad < NQUAD; quad += GBLK) {
        int node = quad * 4 + wave;
        float a0 = 0, a1 = 0, a2 = 0, a3 = 0, a32 = 0;
        int e0 = ptr[node], e1 = ptr[node + 1];
        for (int i = e0 + e; i < e1; i += 8) {
            int s = srcs[i]; float wv = wsv[i];
            const __half* xr = xh + s * ROW1;
            uint2 raw = *(const uint2*)(xr + q * 4);
            float2 f01 = __half22float2(*(__half2*)&raw.x);
            float2 f23 = __half22float2(*(__half2*)&raw.y);
            a0 += fmaxf(f01.x + wv * ew4.x + eb4.x, 0.f);
            a1 += fmaxf(f01.y + wv * ew4.y + eb4.y, 0.f);
            a2 += fmaxf(f23.x + wv * ew4.z + eb4.z, 0.f);
            a3 += fmaxf(f23.y + wv * ew4.w + eb4.w, 0.f);
            if (q == 0) a32 += fmaxf(__half2float(xr[32]) + wv * ew32 + eb32, 0.f);
        }
        #pragma unroll
        for (int m = 8; m <= 32; m <<= 1) {
            a0 += __shfl_xor(a0, m); a1 += __shfl_xor(a1, m);
            a2 += __shfl_xor(a2, m); a3 += __shfl_xor(a3, m);
            a32 += __shfl_xor(a32, m);
        }
        const __half* xn = xh + node * ROW1;
        uint2 sraw = *(const uint2*)(xn + q * 4);
        float2 sf01 = __half22float2(*(__half2*)&sraw.x);
        float2 sf23 = __half22float2(*(__half2*)&sraw.y);
        float hq[4] = {ep * sf01.x + a0, ep * sf01.y + a1,
                       ep * sf23.x + a2, ep * sf23.y + a3};
        float xn32 = (q == 0) ? __half2float(xn[32]) : 0.f;
        float h32 = ep * xn32 + a32;
        int o = lane & 15;
        float tv = b1[o];
        #pragma unroll
        for (int ff = 0; ff < 32; ff++)
            tv += __shfl(hq[ff & 3], ff >> 2) * W1[ff * DIM + o];
        tv += __shfl(h32, 0) * W1[32 * DIM + o];
        tv = fmaxf(tv, 0.f);
        float zv = b2[o];
        #pragma unroll
        for (int ff = 0; ff < DIM; ff++) zv += __shfl(tv, ff) * W2[ff * DIM + o];
        zv = fmaxf(zv, 0.f);
        if (lane < DIM) {
            z[node * DIM + o] = zv;
            rs += zv; rq += zv * zv;
        }
    }
    if (t < 32) s_acc[t] = 0.f;
    __syncthreads();
    if (lane < DIM) { atomicAdd(&s_acc[lane], rs); atomicAdd(&s_acc[16 + lane], rq); }
    __syncthreads();
    if (t < 32) part[blockIdx.x * 32 + t] = s_acc[t];
}

// ---------------- GINE layers 2-5 (16 -> 16): no global atomics ----------------
__global__ void __launch_bounds__(256) k_gine16(
    const __half* __restrict__ xh, const int* __restrict__ ptr,
    const int* __restrict__ srcs, const float* __restrict__ wsv,
    const float* __restrict__ ew, const float* __restrict__ ebv,
    const float* __restrict__ epsp,
    const float* __restrict__ W1, const float* __restrict__ b1,
    const float* __restrict__ W2, const float* __restrict__ b2,
    float* __restrict__ z, float* __restrict__ part) {
    __shared__ float s_acc[32];
    int t = threadIdx.x;
    int wave = t >> 6, lane = t & 63;
    int slot = lane >> 1, h = lane & 1;
    float4 ewlo = ((const float4*)ew)[h * 2];
    float4 ewhi = ((const float4*)ew)[h * 2 + 1];
    float4 eblo = ((const float4*)ebv)[h * 2];
    float4 ebhi = ((const float4*)ebv)[h * 2 + 1];
    float ep = 1.f + epsp[0];
    float rs = 0.f, rq = 0.f;
    for (int quad = blockIdx.x; quad < NQUAD; quad += GBLK) {
        int node = quad * 4 + wave;
        float a[8] = {0, 0, 0, 0, 0, 0, 0, 0};
        int e0 = ptr[node], e1 = ptr[node + 1];
        for (int i = e0 + slot; i < e1; i += 32) {
            int s = srcs[i]; float wv = wsv[i];
            uint4 raw = *(const uint4*)(xh + s * DIM + h * 8);
            float2 f01 = __half22float2(*(__half2*)&raw.x);
            float2 f23 = __half22float2(*(__half2*)&raw.y);
            float2 f45 = __half22float2(*(__half2*)&raw.z);
            float2 f67 = __half22float2(*(__half2*)&raw.w);
            a[0] += fmaxf(f01.x + wv * ewlo.x + eblo.x, 0.f);
            a[1] += fmaxf(f01.y + wv * ewlo.y + eblo.y, 0.f);
            a[2] += fmaxf(f23.x + wv * ewlo.z + eblo.z, 0.f);
            a[3] += fmaxf(f23.y + wv * ewlo.w + eblo.w, 0.f);
            a[4] += fmaxf(f45.x + wv * ewhi.x + ebhi.x, 0.f);
            a[5] += fmaxf(f45.y + wv * ewhi.y + ebhi.y, 0.f);
            a[6] += fmaxf(f67.x + wv * ewhi.z + ebhi.z, 0.f);
            a[7] += fmaxf(f67.y + wv * ewhi.w + ebhi.w, 0.f);
        }
        #pragma unroll
        for (int m = 2; m <= 32; m <<= 1) {
            #pragma unroll
            for (int j = 0; j < 8; j++) a[j] += __shfl_xor(a[j], m);
        }
        uint4 sraw = *(const uint4*)(xh + node * DIM + h * 8);
        float2 s01 = __half22float2(*(__half2*)&sraw.x);
        float2 s23 = __half22float2(*(__half2*)&sraw.y);
        float2 s45 = __half22float2(*(__half2*)&sraw.z);
        float2 s67 = __half22float2(*(__half2*)&sraw.w);
        float hq[8] = {ep * s01.x + a[0], ep * s01.y + a[1], ep * s23.x + a[2],
                       ep * s23.y + a[3], ep * s45.x + a[4], ep * s45.y + a[5],
                       ep * s67.x + a[6], ep * s67.y + a[7]};
        int f = lane & 15;
        float tv = b1[f];
        #pragma unroll
        for (int ff = 0; ff < DIM; ff++)
            tv += __shfl(hq[ff & 7], (ff >> 3) & 1) * W1[ff * DIM + f];
        tv = fmaxf(tv, 0.f);
        float zv = b2[f];
        #pragma unroll
        for (int ff = 0; ff < DIM; ff++) zv += __shfl(tv, ff) * W2[ff * DIM + f];
        zv = fmaxf(zv, 0.f);
        if (lane < DIM) {
            z[node * DIM + f] = zv;
            rs += zv; rq += zv * zv;
        }
    }
    if (t < 32) s_acc[t] = 0.f;
    __syncthreads();
    if (lane < DIM) { atomicAdd(&s_acc[lane], rs); atomicAdd(&s_acc[16 + lane], rq); }
    __syncthreads();
    if (t < 32) part[blockIdx.x * 32 + t] = s_acc[t];
}

// ---------------- reduce block partials -> bnstat[32] ----------------
__global__ void __launch_bounds__(1024) k_bnred(const float* __restrict__ part,
                                                float* __restrict__ bnstat) {
    __shared__ float red[1024];
    int t = threadIdx.x;
    int f = t & 31, g = t >> 5;
    float s = 0.f;
    for (int i = g; i < GBLK; i += 32) s += part[i * 32 + f];
    red[t] = s;
    __syncthreads();
    for (int off = 512; off >= 32; off >>= 1) {
        if (t < off) red[t] += red[t + off];
        __syncthreads();
    }
    if (t < 32) bnstat[t] = red[t];
}

// ---------------- BN normalize: fp32 z -> fp16 x ----------------
__global__ void k_norm(const float* __restrict__ z, __half* __restrict__ xh,
                       const float* __restrict__ bnstat, const float* __restrict__ gamma,
                       const float* __restrict__ beta) {
    int i = blockIdx.x * blockDim.x + threadIdx.x;
    int base = i * 4;
    if (base >= N_NODES * DIM) return;
    float4 zv = *(const float4*)(z + base);
    float zz[4] = {zv.x, zv.y, zv.z, zv.w};
    float out[4];
    int f0 = base & 15;
    const float invn = 1.f / (float)N_NODES;
    #pragma unroll
    for (int j = 0; j < 4; j++) {
        int f = f0 + j;
        float mu = bnstat[f] * invn;
        float var = bnstat[DIM + f] * invn - mu * mu;
        float sc = gamma[f] * rsqrtf(var + BN_EPSV);
        float sh = beta[f] - mu * sc;
        out[j] = zz[j] * sc + sh;
    }
    __half2* dst = (__half2*)(xh + base);
    dst[0] = __floats2half2_rn(out[0], out[1]);
    dst[1] = __floats2half2_rn(out[2], out[3]);
}

// ---------------- hierarchical pooling ----------------
__global__ void __launch_bounds__(256) k_pool(const __half* __restrict__ xh,
                                              const int* __restrict__ batch,
                                              float* __restrict__ gsum,
                                              float* __restrict__ gcnt) {
    __shared__ float lsum[BGR * DIM];
    __shared__ float lcnt[BGR];
    int t = threadIdx.x;
    for (int j = t; j < BGR * DIM; j += 256) lsum[j] = 0.f;
    if (t < BGR) lcnt[t] = 0.f;
    __syncthreads();
    int f = t & 15, r = t >> 4;
    int start = blockIdx.x * POOL_CHUNK;
    float acc = 0.f, cacc = 0.f;
    int cur = -1;
    for (int i = 0; i < POOL_CHUNK / 16; i++) {
        int n = start + r + i * 16;
        if (n >= N_NODES) break;
        int b = batch[n];
        if (b != cur) {
            if (cur >= 0) {
                atomicAdd(&lsum[cur * DIM + f], acc);
                if (f == 0) atomicAdd(&lcnt[cur], cacc);
            }
            cur = b; acc = 0.f; cacc = 0.f;
        }
        acc += __half2float(xh[n * DIM + f]);
        cacc += 1.f;
    }
    if (cur >= 0) {
        atomicAdd(&lsum[cur * DIM + f], acc);
        if (f == 0) atomicAdd(&lcnt[cur], cacc);
    }
    __syncthreads();
    for (int j = t; j < BGR * DIM; j += 256) {
        float v = lsum[j];
        if (v != 0.f) atomicAdd(&gsum[j], v);
    }
    if (t < BGR) {
        float v = lcnt[t];
        if (v != 0.f) atomicAdd(&gcnt[t], v);
    }
}

__global__ void k_xp(const float* __restrict__ gsum, const float* __restrict__ gcnt,
                     const float* __restrict__ w, const float* __restrict__ bias,
                     float* __restrict__ out) {
    int b = blockIdx.x;
    int e = threadIdx.x;
    float inv = 1.f / fmaxf(gcnt[b], 1.f);
    float acc = bias[e];
    #pragma unroll
    for (int f = 0; f < DIM; f++) acc += gsum[b * DIM + f] * inv * w[f * EMB + e];
    out[b * EMB + e] = fmaxf(acc, 0.f);
}

// ---------------- RNA ----------------
__global__ void __launch_bounds__(256) k_bucket(const int* __restrict__ tok, int L, int V,
                                                int* __restrict__ blist,
                                                int* __restrict__ bptr) {
    __shared__ int hist[65];
    __shared__ int cursor[65];
    int b = blockIdx.x, t = threadIdx.x;
    if (t < V) hist[t] = 0;
    __syncthreads();
    for (int l = t; l < L; l += 256) atomicAdd(&hist[tok[b * L + l]], 1);
    __syncthreads();
    if (t == 0) {
        int run = 0;
        for (int v = 0; v < V; v++) {
            cursor[v] = run;
            bptr[b * (V + 1) + v] = run;
            run += hist[v];
        }
        bptr[b * (V + 1) + V] = run;
    }
    __syncthreads();
    for (int l = t; l < L; l += 256) {
        int v = tok[b * L + l];
        int p = atomicAdd(&cursor[v], 1);
        blist[b * L + p] = l;
    }
}

__global__ void __launch_bounds__(256) k_wsum(const int* __restrict__ blist,
                                              const int* __restrict__ bptr,
                                              const float* __restrict__ cw,
                                              float* __restrict__ W, int L, int V) {
    int b = blockIdx.x, v = blockIdx.y;
    int t = threadIdx.x, o = t >> 3, k = t & 7;
    int s = bptr[b * (V + 1) + v], e = bptr[b * (V + 1) + v + 1];
    __shared__ int tk[256];
    const float* cwp = cw + o * (L * KS) + k;
    float acc = 0.f;
    for (int j0 = s; j0 < e; j0 += 256) {
        int lim = e - j0; if (lim > 256) lim = 256;
        __syncthreads();
        if (t < lim) tk[t] = blist[b * L + j0 + t];
        __syncthreads();
        for (int j = 0; j < lim; j++) acc += cwp[tk[j] * KS];
    }
    W[((b * NF + o) * V + v) * KS + k] = acc;
}

__global__ void k_y(const float* __restrict__ Wg, const float* __restrict__ Wl,
                    const float* __restrict__ emb1, const float* __restrict__ emb2,
                    const float* __restrict__ cb1, const float* __restrict__ cb2,
                    float* __restrict__ yg, float* __restrict__ yl) {
    int which = blockIdx.y;
    int bo = blockIdx.x;
    int b = bo >> 5, o = bo & 31;
    int t = threadIdx.x;  // 128
    const float* W = which ? Wl : Wg;
    const float* emb = which ? emb2 : emb1;
    const float* cb = which ? cb2 : cb1;
    float* y = which ? yl : yg;
    int V = which ? 65 : 5;
    __shared__ float Wsh[65 * KS];
    const float* Wrow = W + (b * NF + o) * V * KS;
    for (int j = t; j < V * KS; j += 128) Wsh[j] = Wrow[j];
    __syncthreads();
    if (t < OUTT) {
        float acc = cb[o];
        for (int v = 0; v < V; v++) {
            const float* ep = emb + v * EMB + t;
            #pragma unroll
            for (int k = 0; k < KS; k++) acc += Wsh[v * KS + k] * ep[k];
        }
        y[(b * NF + o) * OUTT + t] = acc;
    }
}

__global__ void k_fc(const float* __restrict__ yg, const float* __restrict__ yl,
                     const float* __restrict__ w, const float* __restrict__ bias,
                     float* __restrict__ xrg, float* __restrict__ xrl) {
    int b = blockIdx.x;
    int which = blockIdx.y;
    const float* y = which ? yl : yg;
    float* xr = which ? xrl : xrg;
    int e = threadIdx.x;  // 128
    __shared__ float ych[128];
    float acc = bias[e];
    for (int j0 = 0; j0 < FC_IN; j0 += 128) {
        __syncthreads();
        int lim = FC_IN - j0; if (lim > 128) lim = 128;
        if (e < lim) ych[e] = y[b * FC_IN + j0 + e];
        __syncthreads();
        for (int jj = 0; jj < lim; jj++) acc += ych[jj] * w[(j0 + jj) * EMB + e];
    }
    xr[b * EMB + e] = acc;
}

__global__ void k_comb(const float* __restrict__ xrg, const float* __restrict__ xrl,
                       float* __restrict__ out) {
    int i = blockIdx.x * blockDim.x + threadIdx.x;
    if (i < BGR * EMB) out[i] = 0.5f * (xrg[i] + xrl[i]);
}

extern "C" void kernel_launch(void* const* d_in, const int* in_sizes, int n_in,
                              void* d_out, int out_size, void* d_ws, size_t ws_size,
                              hipStream_t stream) {
    const float* pro_x = (const float*)d_in[0];
    const int* eidx = (const int*)d_in[1];
    const int* esrc = eidx;
    const int* edst = eidx + N_EDGES;
    const float* pw = (const float*)d_in[2];
    const int* batch = (const int*)d_in[3];
    const int* rg = (const int*)d_in[4];
    const int* rl = (const int*)d_in[5];
    const float* g1_w1 = (const float*)d_in[6];
    const float* g1_b1 = (const float*)d_in[7];
    const float* g1_w2 = (const float*)d_in[8];
    const float* g1_b2 = (const float*)d_in[9];
    const float* g1_ew = (const float*)d_in[10];
    const float* g1_eb = (const float*)d_in[11];
    const float* g1_eps = (const float*)d_in[12];
    const float* g_w1 = (const float*)d_in[13];
    const float* g_b1 = (const float*)d_in[14];
    const float* g_w2 = (const float*)d_in[15];
    const float* g_b2 = (const float*)d_in[16];
    const float* g_ew = (const float*)d_in[17];
    const float* g_eb = (const float*)d_in[18];
    const float* g_eps = (const float*)d_in[19];
    const float* bn_gamma = (const float*)d_in[20];
    const float* bn_beta = (const float*)d_in[21];
    const float* fc1_xp_w = (const float*)d_in[22];
    const float* fc1_xp_b = (const float*)d_in[23];
    const float* emb1 = (const float*)d_in[24];
    const float* emb2 = (const float*)d_in[25];
    const float* convr1_w = (const float*)d_in[26];
    const float* convr1_b = (const float*)d_in[27];
    const float* convr2_w = (const float*)d_in[28];
    const float* convr2_b = (const float*)d_in[29];
    const float* fcxr_w = (const float*)d_in[30];
    const float* fcxr_b = (const float*)d_in[31];
    float* out = (float*)d_out;

    float* wsf = (float*)d_ws;
    int* ptr     = (int*)wsf;          wsf += 100096;
    int* cnt     = (int*)wsf;          wsf += 100096;
    int* cursor  = (int*)wsf;          wsf += 100096;
    int* src_s   = (int*)wsf;          wsf += N_EDGES;
    float* w_s   = wsf;                wsf += N_EDGES;
    float* z     = wsf;                wsf += N_NODES * DIM;
    __half* xh   = (__half*)wsf;       wsf += N_NODES * DIM / 2;
    __half* xh1  = (__half*)wsf;       wsf += N_NODES * ROW1 / 2;
    float* stats = wsf;                wsf += 1280;
    float* bpart = wsf;                wsf += GBLK * 32;     // BN block partials
    float* Wg    = wsf;                wsf += BGR * NF * 5 * KS;
    float* Wl    = wsf;                wsf += BGR * NF * 65 * KS;
    float* yg    = wsf;                wsf += BGR * NF * OUTT;
    float* yl    = wsf;                wsf += BGR * NF * OUTT;
    float* xrg   = wsf;                wsf += BGR * EMB;
    float* xrl   = wsf;                wsf += BGR * EMB;
    int* blg     = (int*)wsf;          wsf += BGR * MAXLEN;
    int* bll     = (int*)wsf;          wsf += BGR * LOCLEN;
    int* bpg     = (int*)wsf;          wsf += BGR * 6;
    int* bpl     = (int*)wsf;          wsf += BGR * 66;
    float* gsum   = stats;
    float* gcnt   = stats + 1024;
    float* bnstat = stats + 1088;

    hipMemsetAsync(cnt, 0, N_NODES * sizeof(int), stream);
    hipMemsetAsync(stats, 0, 1280 * sizeof(float), stream);

    // CSR build
    k_count<<<N_EDGES / 256, 256, 0, stream>>>(edst, cnt);
    k_scan<<<1, 1024, 0, stream>>>(cnt, ptr, cursor);
    k_scatter<<<N_EDGES / 256, 256, 0, stream>>>(esrc, edst, pw, cursor, src_s, w_s);

    // pro_x -> fp16 padded rows
    k_half1<<<(N_NODES * NFP + 255) / 256, 256, 0, stream>>>(pro_x, xh1);

    // RNA branch
    k_bucket<<<BGR, 256, 0, stream>>>(rg, MAXLEN, 5, blg, bpg);
    k_bucket<<<BGR, 256, 0, stream>>>(rl, LOCLEN, 65, bll, bpl);
    k_wsum<<<dim3(BGR, 5), 256, 0, stream>>>(blg, bpg, convr1_w, Wg, MAXLEN, 5);
    k_wsum<<<dim3(BGR, 65), 256, 0, stream>>>(bll, bpl, convr2_w, Wl, LOCLEN, 65);
    k_y<<<dim3(BGR * NF, 2), 128, 0, stream>>>(Wg, Wl, emb1, emb2, convr1_b, convr2_b, yg, yl);
    k_fc<<<dim3(BGR, 2), 128, 0, stream>>>(yg, yl, fcxr_w, fcxr_b, xrg, xrl);
    k_comb<<<(BGR * EMB + 255) / 256, 256, 0, stream>>>(xrg, xrl, out);

    // GNN stack
    int nblocks = (N_NODES * DIM / 4 + 255) / 256;
    k_gine1<<<GBLK, 256, 0, stream>>>(xh1, ptr, src_s, w_s, g1_ew, g1_eb, g1_eps,
                                      g1_w1, g1_b1, g1_w2, g1_b2, z, bpart);
    k_bnred<<<1, 1024, 0, stream>>>(bpart, bnstat);
    k_norm<<<nblocks, 256, 0, stream>>>(z, xh, bnstat, bn_gamma, bn_beta);
    for (int i = 0; i < 4; i++) {
        k_gine16<<<GBLK, 256, 0, stream>>>(xh, ptr, src_s, w_s,
                                           g_ew + i * DIM, g_eb + i * DIM, g_eps + i,
                                           g_w1 + i * DIM * DIM, g_b1 + i * DIM,
                                           g_w2 + i * DIM * DIM, g_b2 + i * DIM,
                                           z, bpart);
        k_bnred<<<1, 1024, 0, stream>>>(bpart, bnstat + (i + 1) * 32);
        k_norm<<<nblocks, 256, 0, stream>>>(z, xh, bnstat + (i + 1) * 32,
                                            bn_gamma + (i + 1) * DIM, bn_beta + (i + 1) * DIM);
    }
    k_pool<<<(N_NODES + POOL_CHUNK - 1) / POOL_CHUNK, 256, 0, stream>>>(xh, batch, gsum, gcnt);
    k_xp<<<BGR, EMB, 0, stream>>>(gsum, gcnt, fc1_xp_w, fc1_xp_b, out + BGR * EMB);
}

// Round 6
// 1477.815 us; speedup vs baseline: 2.6602x; 1.2307x over previous
//
#include <hip/hip_runtime.h>
#include <hip/hip_fp16.h>

#define N_NODES 100000
#define N_EDGES 3200000
#define BGR 64
#define DIM 16
#define NFP 33
#define ROW1 36   // padded half-row for pro_x (72B)
#define EMB 128
#define MAXLEN 3000
#define LOCLEN 2998
#define NF 32
#define KS 8
#define OUTT 121
#define FC_IN 3872
#define BN_EPSV 1e-5f
#define POOL_CHUNK 2048
#define NQUAD 25000      // N_NODES / 4
#define GBLK 3125        // gine grid: each block handles 8 quads
#define SCAN_BLOCKS 98   // ceil(100000/1024)

// ---------------- CSR build ----------------
__global__ void k_count(const int* __restrict__ dst, int* __restrict__ cnt) {
    int i = blockIdx.x * blockDim.x + threadIdx.x;
    if (i < N_EDGES) atomicAdd(&cnt[dst[i]], 1);
}

// phase A: per-block (1024 elems) exclusive scan + block sums
__global__ void __launch_bounds__(1024) k_scanA(const int* __restrict__ cnt,
                                                int* __restrict__ ptrloc,
                                                int* __restrict__ bsum) {
    __shared__ int sh[1024];
    int t = threadIdx.x;
    int g = blockIdx.x * 1024 + t;
    int c = (g < N_NODES) ? cnt[g] : 0;
    sh[t] = c;
    __syncthreads();
    for (int off = 1; off < 1024; off <<= 1) {
        int v = (t >= off) ? sh[t - off] : 0;
        __syncthreads();
        sh[t] += v;
        __syncthreads();
    }
    if (g < N_NODES) ptrloc[g] = sh[t] - c;
    if (t == 1023) bsum[blockIdx.x] = sh[1023];
}

// phase B: scan the 98 block sums (1 tiny block)
__global__ void __launch_bounds__(128) k_scanB(const int* __restrict__ bsum,
                                               int* __restrict__ boff) {
    __shared__ int sh[128];
    int t = threadIdx.x;
    int v = (t < SCAN_BLOCKS) ? bsum[t] : 0;
    sh[t] = v;
    __syncthreads();
    for (int off = 1; off < 128; off <<= 1) {
        int u = (t >= off) ? sh[t - off] : 0;
        __syncthreads();
        sh[t] += u;
        __syncthreads();
    }
    if (t < SCAN_BLOCKS) boff[t] = sh[t] - v;
}

// phase C: add block offsets, produce ptr & cursor
__global__ void k_scanC(const int* __restrict__ ptrloc, const int* __restrict__ boff,
                        int* __restrict__ ptr, int* __restrict__ cursor) {
    int i = blockIdx.x * blockDim.x + threadIdx.x;
    if (i < N_NODES) {
        int p = ptrloc[i] + boff[i >> 10];
        ptr[i] = p;
        cursor[i] = p;
    }
    if (i == 0) ptr[N_NODES] = N_EDGES;
}

__global__ void k_scatter(const int* __restrict__ src, const int* __restrict__ dst,
                          const float* __restrict__ w, int* __restrict__ cursor,
                          int2* __restrict__ er) {
    int i = blockIdx.x * blockDim.x + threadIdx.x;
    if (i < N_EDGES) {
        int d = dst[i];
        int p = atomicAdd(&cursor[d], 1);
        er[p] = make_int2(src[i], __float_as_int(w[i]));
    }
}

// ---------------- fp16 conversion of pro_x ----------------
__global__ void k_half1(const float* __restrict__ x, __half* __restrict__ xh) {
    int i = blockIdx.x * blockDim.x + threadIdx.x;
    if (i < N_NODES * NFP) {
        int n = i / NFP, f = i - n * NFP;
        xh[n * ROW1 + f] = __float2half(x[i]);
    }
}

// ---------------- GINE layer 1 (33 -> 16) ----------------
__global__ void __launch_bounds__(256) k_gine1(
    const __half* __restrict__ xh, const int* __restrict__ ptr,
    const int2* __restrict__ er,
    const float* __restrict__ ew, const float* __restrict__ ebv,
    const float* __restrict__ epsp,
    const float* __restrict__ W1, const float* __restrict__ b1,
    const float* __restrict__ W2, const float* __restrict__ b2,
    float* __restrict__ z, float* __restrict__ part) {
    __shared__ float s_acc[32];
    int t = threadIdx.x;
    int wave = t >> 6, lane = t & 63;
    int e = lane >> 3, q = lane & 7;
    float4 ew4 = ((const float4*)ew)[q];
    float4 eb4 = ((const float4*)ebv)[q];
    float ew32 = ew[32], eb32 = ebv[32];
    float ep = 1.f + epsp[0];
    float rs = 0.f, rq = 0.f;
    for (int quad = blockIdx.x; quad < NQUAD; quad += GBLK) {
        int node = quad * 4 + wave;
        float a0 = 0, a1 = 0, a2 = 0, a3 = 0, a32 = 0;
        int e0 = ptr[node], e1 = ptr[node + 1];
        for (int i = e0 + e; i < e1; i += 8) {
            int2 ed = er[i];
            int s = ed.x; float wv = __int_as_float(ed.y);
            const __half* xr = xh + s * ROW1;
            uint2 raw = *(const uint2*)(xr + q * 4);
            float2 f01 = __half22float2(*(__half2*)&raw.x);
            float2 f23 = __half22float2(*(__half2*)&raw.y);
            a0 += fmaxf(f01.x + wv * ew4.x + eb4.x, 0.f);
            a1 += fmaxf(f01.y + wv * ew4.y + eb4.y, 0.f);
            a2 += fmaxf(f23.x + wv * ew4.z + eb4.z, 0.f);
            a3 += fmaxf(f23.y + wv * ew4.w + eb4.w, 0.f);
            if (q == 0) a32 += fmaxf(__half2float(xr[32]) + wv * ew32 + eb32, 0.f);
        }
        #pragma unroll
        for (int m = 8; m <= 32; m <<= 1) {
            a0 += __shfl_xor(a0, m); a1 += __shfl_xor(a1, m);
            a2 += __shfl_xor(a2, m); a3 += __shfl_xor(a3, m);
            a32 += __shfl_xor(a32, m);
        }
        const __half* xn = xh + node * ROW1;
        uint2 sraw = *(const uint2*)(xn + q * 4);
        float2 sf01 = __half22float2(*(__half2*)&sraw.x);
        float2 sf23 = __half22float2(*(__half2*)&sraw.y);
        float hq[4] = {ep * sf01.x + a0, ep * sf01.y + a1,
                       ep * sf23.x + a2, ep * sf23.y + a3};
        float xn32 = (q == 0) ? __half2float(xn[32]) : 0.f;
        float h32 = ep * xn32 + a32;
        int o = lane & 15;
        float tv = b1[o];
        #pragma unroll
        for (int ff = 0; ff < 32; ff++)
            tv += __shfl(hq[ff & 3], ff >> 2) * W1[ff * DIM + o];
        tv += __shfl(h32, 0) * W1[32 * DIM + o];
        tv = fmaxf(tv, 0.f);
        float zv = b2[o];
        #pragma unroll
        for (int ff = 0; ff < DIM; ff++) zv += __shfl(tv, ff) * W2[ff * DIM + o];
        zv = fmaxf(zv, 0.f);
        if (lane < DIM) {
            z[node * DIM + o] = zv;
            rs += zv; rq += zv * zv;
        }
    }
    if (t < 32) s_acc[t] = 0.f;
    __syncthreads();
    if (lane < DIM) { atomicAdd(&s_acc[lane], rs); atomicAdd(&s_acc[16 + lane], rq); }
    __syncthreads();
    if (t < 32) part[blockIdx.x * 32 + t] = s_acc[t];
}

// ---------------- GINE layers 2-5 (16 -> 16) ----------------
__global__ void __launch_bounds__(256) k_gine16(
    const __half* __restrict__ xh, const int* __restrict__ ptr,
    const int2* __restrict__ er,
    const float* __restrict__ ew, const float* __restrict__ ebv,
    const float* __restrict__ epsp,
    const float* __restrict__ W1, const float* __restrict__ b1,
    const float* __restrict__ W2, const float* __restrict__ b2,
    float* __restrict__ z, float* __restrict__ part) {
    __shared__ float s_acc[32];
    int t = threadIdx.x;
    int wave = t >> 6, lane = t & 63;
    int slot = lane >> 1, h = lane & 1;
    float4 ewlo = ((const float4*)ew)[h * 2];
    float4 ewhi = ((const float4*)ew)[h * 2 + 1];
    float4 eblo = ((const float4*)ebv)[h * 2];
    float4 ebhi = ((const float4*)ebv)[h * 2 + 1];
    float ep = 1.f + epsp[0];
    float rs = 0.f, rq = 0.f;
    for (int quad = blockIdx.x; quad < NQUAD; quad += GBLK) {
        int node = quad * 4 + wave;
        float a[8] = {0, 0, 0, 0, 0, 0, 0, 0};
        int e0 = ptr[node], e1 = ptr[node + 1];
        for (int i = e0 + slot; i < e1; i += 32) {
            int2 ed = er[i];
            int s = ed.x; float wv = __int_as_float(ed.y);
            uint4 raw = *(const uint4*)(xh + s * DIM + h * 8);
            float2 f01 = __half22float2(*(__half2*)&raw.x);
            float2 f23 = __half22float2(*(__half2*)&raw.y);
            float2 f45 = __half22float2(*(__half2*)&raw.z);
            float2 f67 = __half22float2(*(__half2*)&raw.w);
            a[0] += fmaxf(f01.x + wv * ewlo.x + eblo.x, 0.f);
            a[1] += fmaxf(f01.y + wv * ewlo.y + eblo.y, 0.f);
            a[2] += fmaxf(f23.x + wv * ewlo.z + eblo.z, 0.f);
            a[3] += fmaxf(f23.y + wv * ewlo.w + eblo.w, 0.f);
            a[4] += fmaxf(f45.x + wv * ewhi.x + ebhi.x, 0.f);
            a[5] += fmaxf(f45.y + wv * ewhi.y + ebhi.y, 0.f);
            a[6] += fmaxf(f67.x + wv * ewhi.z + ebhi.z, 0.f);
            a[7] += fmaxf(f67.y + wv * ewhi.w + ebhi.w, 0.f);
        }
        #pragma unroll
        for (int m = 2; m <= 32; m <<= 1) {
            #pragma unroll
            for (int j = 0; j < 8; j++) a[j] += __shfl_xor(a[j], m);
        }
        uint4 sraw = *(const uint4*)(xh + node * DIM + h * 8);
        float2 s01 = __half22float2(*(__half2*)&sraw.x);
        float2 s23 = __half22float2(*(__half2*)&sraw.y);
        float2 s45 = __half22float2(*(__half2*)&sraw.z);
        float2 s67 = __half22float2(*(__half2*)&sraw.w);
        float hq[8] = {ep * s01.x + a[0], ep * s01.y + a[1], ep * s23.x + a[2],
                       ep * s23.y + a[3], ep * s45.x + a[4], ep * s45.y + a[5],
                       ep * s67.x + a[6], ep * s67.y + a[7]};
        int f = lane & 15;
        float tv = b1[f];
        #pragma unroll
        for (int ff = 0; ff < DIM; ff++)
            tv += __shfl(hq[ff & 7], (ff >> 3) & 1) * W1[ff * DIM + f];
        tv = fmaxf(tv, 0.f);
        float zv = b2[f];
        #pragma unroll
        for (int ff = 0; ff < DIM; ff++) zv += __shfl(tv, ff) * W2[ff * DIM + f];
        zv = fmaxf(zv, 0.f);
        if (lane < DIM) {
            z[node * DIM + f] = zv;
            rs += zv; rq += zv * zv;
        }
    }
    if (t < 32) s_acc[t] = 0.f;
    __syncthreads();
    if (lane < DIM) { atomicAdd(&s_acc[lane], rs); atomicAdd(&s_acc[16 + lane], rq); }
    __syncthreads();
    if (t < 32) part[blockIdx.x * 32 + t] = s_acc[t];
}

// ---------------- reduce block partials -> bnstat[32] ----------------
__global__ void __launch_bounds__(1024) k_bnred(const float* __restrict__ part,
                                                float* __restrict__ bnstat) {
    __shared__ float red[1024];
    int t = threadIdx.x;
    int f = t & 31, g = t >> 5;
    float s = 0.f;
    for (int i = g; i < GBLK; i += 32) s += part[i * 32 + f];
    red[t] = s;
    __syncthreads();
    for (int off = 512; off >= 32; off >>= 1) {
        if (t < off) red[t] += red[t + off];
        __syncthreads();
    }
    if (t < 32) bnstat[t] = red[t];
}

// ---------------- BN normalize: fp32 z -> fp16 x ----------------
__global__ void k_norm(const float* __restrict__ z, __half* __restrict__ xh,
                       const float* __restrict__ bnstat, const float* __restrict__ gamma,
                       const float* __restrict__ beta) {
    int i = blockIdx.x * blockDim.x + threadIdx.x;
    int base = i * 4;
    if (base >= N_NODES * DIM) return;
    float4 zv = *(const float4*)(z + base);
    float zz[4] = {zv.x, zv.y, zv.z, zv.w};
    float out[4];
    int f0 = base & 15;
    const float invn = 1.f / (float)N_NODES;
    #pragma unroll
    for (int j = 0; j < 4; j++) {
        int f = f0 + j;
        float mu = bnstat[f] * invn;
        float var = bnstat[DIM + f] * invn - mu * mu;
        float sc = gamma[f] * rsqrtf(var + BN_EPSV);
        float sh = beta[f] - mu * sc;
        out[j] = zz[j] * sc + sh;
    }
    __half2* dst = (__half2*)(xh + base);
    dst[0] = __floats2half2_rn(out[0], out[1]);
    dst[1] = __floats2half2_rn(out[2], out[3]);
}

// ---------------- hierarchical pooling ----------------
__global__ void __launch_bounds__(256) k_pool(const __half* __restrict__ xh,
                                              const int* __restrict__ batch,
                                              float* __restrict__ gsum,
                                              float* __restrict__ gcnt) {
    __shared__ float lsum[BGR * DIM];
    __shared__ float lcnt[BGR];
    int t = threadIdx.x;
    for (int j = t; j < BGR * DIM; j += 256) lsum[j] = 0.f;
    if (t < BGR) lcnt[t] = 0.f;
    __syncthreads();
    int f = t & 15, r = t >> 4;
    int start = blockIdx.x * POOL_CHUNK;
    float acc = 0.f, cacc = 0.f;
    int cur = -1;
    for (int i = 0; i < POOL_CHUNK / 16; i++) {
        int n = start + r + i * 16;
        if (n >= N_NODES) break;
        int b = batch[n];
        if (b != cur) {
            if (cur >= 0) {
                atomicAdd(&lsum[cur * DIM + f], acc);
                if (f == 0) atomicAdd(&lcnt[cur], cacc);
            }
            cur = b; acc = 0.f; cacc = 0.f;
        }
        acc += __half2float(xh[n * DIM + f]);
        cacc += 1.f;
    }
    if (cur >= 0) {
        atomicAdd(&lsum[cur * DIM + f], acc);
        if (f == 0) atomicAdd(&lcnt[cur], cacc);
    }
    __syncthreads();
    for (int j = t; j < BGR * DIM; j += 256) {
        float v = lsum[j];
        if (v != 0.f) atomicAdd(&gsum[j], v);
    }
    if (t < BGR) {
        float v = lcnt[t];
        if (v != 0.f) atomicAdd(&gcnt[t], v);
    }
}

__global__ void k_xp(const float* __restrict__ gsum, const float* __restrict__ gcnt,
                     const float* __restrict__ w, const float* __restrict__ bias,
                     float* __restrict__ out) {
    int b = blockIdx.x;
    int e = threadIdx.x;
    float inv = 1.f / fmaxf(gcnt[b], 1.f);
    float acc = bias[e];
    #pragma unroll
    for (int f = 0; f < DIM; f++) acc += gsum[b * DIM + f] * inv * w[f * EMB + e];
    out[b * EMB + e] = fmaxf(acc, 0.f);
}

// ---------------- RNA ----------------
__global__ void __launch_bounds__(256) k_bucket(const int* __restrict__ tok, int L, int V,
                                                int* __restrict__ blist,
                                                int* __restrict__ bptr) {
    __shared__ int hist[65];
    __shared__ int cursor[65];
    int b = blockIdx.x, t = threadIdx.x;
    if (t < V) hist[t] = 0;
    __syncthreads();
    for (int l = t; l < L; l += 256) atomicAdd(&hist[tok[b * L + l]], 1);
    __syncthreads();
    if (t == 0) {
        int run = 0;
        for (int v = 0; v < V; v++) {
            cursor[v] = run;
            bptr[b * (V + 1) + v] = run;
            run += hist[v];
        }
        bptr[b * (V + 1) + V] = run;
    }
    __syncthreads();
    for (int l = t; l < L; l += 256) {
        int v = tok[b * L + l];
        int p = atomicAdd(&cursor[v], 1);
        blist[b * L + p] = l;
    }
}

__global__ void __launch_bounds__(256) k_wsum(const int* __restrict__ blist,
                                              const int* __restrict__ bptr,
                                              const float* __restrict__ cw,
                                              float* __restrict__ W, int L, int V) {
    int b = blockIdx.x, v = blockIdx.y;
    int t = threadIdx.x, o = t >> 3, k = t & 7;
    int s = bptr[b * (V + 1) + v], e = bptr[b * (V + 1) + v + 1];
    __shared__ int tk[256];
    const float* cwp = cw + o * (L * KS) + k;
    float acc = 0.f;
    for (int j0 = s; j0 < e; j0 += 256) {
        int lim = e - j0; if (lim > 256) lim = 256;
        __syncthreads();
        if (t < lim) tk[t] = blist[b * L + j0 + t];
        __syncthreads();
        for (int j = 0; j < lim; j++) acc += cwp[tk[j] * KS];
    }
    W[((b * NF + o) * V + v) * KS + k] = acc;
}

__global__ void k_y(const float* __restrict__ Wg, const float* __restrict__ Wl,
                    const float* __restrict__ emb1, const float* __restrict__ emb2,
                    const float* __restrict__ cb1, const float* __restrict__ cb2,
                    float* __restrict__ yg, float* __restrict__ yl) {
    int which = blockIdx.y;
    int bo = blockIdx.x;
    int b = bo >> 5, o = bo & 31;
    int t = threadIdx.x;  // 128
    const float* W = which ? Wl : Wg;
    const float* emb = which ? emb2 : emb1;
    const float* cb = which ? cb2 : cb1;
    float* y = which ? yl : yg;
    int V = which ? 65 : 5;
    __shared__ float Wsh[65 * KS];
    const float* Wrow = W + (b * NF + o) * V * KS;
    for (int j = t; j < V * KS; j += 128) Wsh[j] = Wrow[j];
    __syncthreads();
    if (t < OUTT) {
        float acc = cb[o];
        for (int v = 0; v < V; v++) {
            const float* ep = emb + v * EMB + t;
            #pragma unroll
            for (int k = 0; k < KS; k++) acc += Wsh[v * KS + k] * ep[k];
        }
        y[(b * NF + o) * OUTT + t] = acc;
    }
}

__global__ void k_fc(const float* __restrict__ yg, const float* __restrict__ yl,
                     const float* __restrict__ w, const float* __restrict__ bias,
                     float* __restrict__ xrg, float* __restrict__ xrl) {
    int b = blockIdx.x;
    int which = blockIdx.y;
    const float* y = which ? yl : yg;
    float* xr = which ? xrl : xrg;
    int e = threadIdx.x;  // 128
    __shared__ float ych[128];
    float acc = bias[e];
    for (int j0 = 0; j0 < FC_IN; j0 += 128) {
        __syncthreads();
        int lim = FC_IN - j0; if (lim > 128) lim = 128;
        if (e < lim) ych[e] = y[b * FC_IN + j0 + e];
        __syncthreads();
        for (int jj = 0; jj < lim; jj++) acc += ych[jj] * w[(j0 + jj) * EMB + e];
    }
    xr[b * EMB + e] = acc;
}

__global__ void k_comb(const float* __restrict__ xrg, const float* __restrict__ xrl,
                       float* __restrict__ out) {
    int i = blockIdx.x * blockDim.x + threadIdx.x;
    if (i < BGR * EMB) out[i] = 0.5f * (xrg[i] + xrl[i]);
}

extern "C" void kernel_launch(void* const* d_in, const int* in_sizes, int n_in,
                              void* d_out, int out_size, void* d_ws, size_t ws_size,
                              hipStream_t stream) {
    const float* pro_x = (const float*)d_in[0];
    const int* eidx = (const int*)d_in[1];
    const int* esrc = eidx;
    const int* edst = eidx + N_EDGES;
    const float* pw = (const float*)d_in[2];
    const int* batch = (const int*)d_in[3];
    const int* rg = (const int*)d_in[4];
    const int* rl = (const int*)d_in[5];
    const float* g1_w1 = (const float*)d_in[6];
    const float* g1_b1 = (const float*)d_in[7];
    const float* g1_w2 = (const float*)d_in[8];
    const float* g1_b2 = (const float*)d_in[9];
    const float* g1_ew = (const float*)d_in[10];
    const float* g1_eb = (const float*)d_in[11];
    const float* g1_eps = (const float*)d_in[12];
    const float* g_w1 = (const float*)d_in[13];
    const float* g_b1 = (const float*)d_in[14];
    const float* g_w2 = (const float*)d_in[15];
    const float* g_b2 = (const float*)d_in[16];
    const float* g_ew = (const float*)d_in[17];
    const float* g_eb = (const float*)d_in[18];
    const float* g_eps = (const float*)d_in[19];
    const float* bn_gamma = (const float*)d_in[20];
    const float* bn_beta = (const float*)d_in[21];
    const float* fc1_xp_w = (const float*)d_in[22];
    const float* fc1_xp_b = (const float*)d_in[23];
    const float* emb1 = (const float*)d_in[24];
    const float* emb2 = (const float*)d_in[25];
    const float* convr1_w = (const float*)d_in[26];
    const float* convr1_b = (const float*)d_in[27];
    const float* convr2_w = (const float*)d_in[28];
    const float* convr2_b = (const float*)d_in[29];
    const float* fcxr_w = (const float*)d_in[30];
    const float* fcxr_b = (const float*)d_in[31];
    float* out = (float*)d_out;

    float* wsf = (float*)d_ws;
    int* ptr     = (int*)wsf;          wsf += 100096;
    int* cnt     = (int*)wsf;          wsf += 100096;
    int* cursor  = (int*)wsf;          wsf += 100096;
    int* ptrloc  = (int*)wsf;          wsf += 100096;
    int* bsum    = (int*)wsf;          wsf += 128;
    int* boff    = (int*)wsf;          wsf += 128;
    int2* er     = (int2*)wsf;         wsf += 2 * N_EDGES;
    float* z     = wsf;                wsf += N_NODES * DIM;
    __half* xh   = (__half*)wsf;       wsf += N_NODES * DIM / 2;
    __half* xh1  = (__half*)wsf;       wsf += N_NODES * ROW1 / 2;
    float* stats = wsf;                wsf += 1280;
    float* bpart = wsf;                wsf += GBLK * 32;
    float* Wg    = wsf;                wsf += BGR * NF * 5 * KS;
    float* Wl    = wsf;                wsf += BGR * NF * 65 * KS;
    float* yg    = wsf;                wsf += BGR * NF * OUTT;
    float* yl    = wsf;                wsf += BGR * NF * OUTT;
    float* xrg   = wsf;                wsf += BGR * EMB;
    float* xrl   = wsf;                wsf += BGR * EMB;
    int* blg     = (int*)wsf;          wsf += BGR * MAXLEN;
    int* bll     = (int*)wsf;          wsf += BGR * LOCLEN;
    int* bpg     = (int*)wsf;          wsf += BGR * 6;
    int* bpl     = (int*)wsf;          wsf += BGR * 66;
    float* gsum   = stats;
    float* gcnt   = stats + 1024;
    float* bnstat = stats + 1088;

    hipMemsetAsync(cnt, 0, N_NODES * sizeof(int), stream);
    hipMemsetAsync(stats, 0, 1280 * sizeof(float), stream);

    // CSR build
    k_count<<<N_EDGES / 256, 256, 0, stream>>>(edst, cnt);
    k_scanA<<<SCAN_BLOCKS, 1024, 0, stream>>>(cnt, ptrloc, bsum);
    k_scanB<<<1, 128, 0, stream>>>(bsum, boff);
    k_scanC<<<(N_NODES + 255) / 256, 256, 0, stream>>>(ptrloc, boff, ptr, cursor);
    k_scatter<<<N_EDGES / 256, 256, 0, stream>>>(esrc, edst, pw, cursor, er);

    // pro_x -> fp16 padded rows
    k_half1<<<(N_NODES * NFP + 255) / 256, 256, 0, stream>>>(pro_x, xh1);

    // RNA branch
    k_bucket<<<BGR, 256, 0, stream>>>(rg, MAXLEN, 5, blg, bpg);
    k_bucket<<<BGR, 256, 0, stream>>>(rl, LOCLEN, 65, bll, bpl);
    k_wsum<<<dim3(BGR, 5), 256, 0, stream>>>(blg, bpg, convr1_w, Wg, MAXLEN, 5);
    k_wsum<<<dim3(BGR, 65), 256, 0, stream>>>(bll, bpl, convr2_w, Wl, LOCLEN, 65);
    k_y<<<dim3(BGR * NF, 2), 128, 0, stream>>>(Wg, Wl, emb1, emb2, convr1_b, convr2_b, yg, yl);
    k_fc<<<dim3(BGR, 2), 128, 0, stream>>>(yg, yl, fcxr_w, fcxr_b, xrg, xrl);
    k_comb<<<(BGR * EMB + 255) / 256, 256, 0, stream>>>(xrg, xrl, out);

    // GNN stack
    int nblocks = (N_NODES * DIM / 4 + 255) / 256;
    k_gine1<<<GBLK, 256, 0, stream>>>(xh1, ptr, er, g1_ew, g1_eb, g1_eps,
                                      g1_w1, g1_b1, g1_w2, g1_b2, z, bpart);
    k_bnred<<<1, 1024, 0, stream>>>(bpart, bnstat);
    k_norm<<<nblocks, 256, 0, stream>>>(z, xh, bnstat, bn_gamma, bn_beta);
    for (int i = 0; i < 4; i++) {
        k_gine16<<<GBLK, 256, 0, stream>>>(xh, ptr, er,
                                           g_ew + i * DIM, g_eb + i * DIM, g_eps + i,
                                           g_w1 + i * DIM * DIM, g_b1 + i * DIM,
                                           g_w2 + i * DIM * DIM, g_b2 + i * DIM,
                                           z, bpart);
        k_bnred<<<1, 1024, 0, stream>>>(bpart, bnstat + (i + 1) * 32);
        k_norm<<<nblocks, 256, 0, stream>>>(z, xh, bnstat + (i + 1) * 32,
                                            bn_gamma + (i + 1) * DIM, bn_beta + (i + 1) * DIM);
    }
    k_pool<<<(N_NODES + POOL_CHUNK - 1) / POOL_CHUNK, 256, 0, stream>>>(xh, batch, gsum, gcnt);
    k_xp<<<BGR, EMB, 0, stream>>>(gsum, gcnt, fc1_xp_w, fc1_xp_b, out + BGR * EMB);
}

// Round 7
// 1317.584 us; speedup vs baseline: 2.9837x; 1.1216x over previous
//
#include <hip/hip_runtime.h>
#include <hip/hip_fp16.h>

#define N_NODES 100000
#define N_EDGES 3200000
#define BGR 64
#define DIM 16
#define NFP 33
#define ROW1 36   // padded half-row for pro_x (72B)
#define EMB 128
#define MAXLEN 3000
#define LOCLEN 2998
#define NF 32
#define KS 8
#define OUTT 121
#define FC_IN 3872
#define BN_EPSV 1e-5f
#define POOL_CHUNK 2048
#define NQUAD 25000      // N_NODES / 4
#define GBLK 3125        // gine grid
// binned CSR build
#define NBIN 391         // ceil(100000/256), 256 nodes per bin
#define BCNT_BLK 512     // bincnt blocks (E/512 = 6250 each)
#define P1_CHUNK 4096
#define P1_BLOCKS 782    // ceil(E/4096)
#define MAXBIN 9088      // bin capacity (mean 8184, +10 sigma)

// ---------------- CSR build: bin counts ----------------
__global__ void __launch_bounds__(256) k_bincnt(const int* __restrict__ dst,
                                                int* __restrict__ bh) {
    __shared__ int hist[NBIN];
    int t = threadIdx.x, bid = blockIdx.x;
    for (int b = t; b < NBIN; b += 256) hist[b] = 0;
    __syncthreads();
    int e0 = bid * (N_EDGES / BCNT_BLK);
    int e1 = e0 + (N_EDGES / BCNT_BLK);
    for (int e = e0 + t; e < e1; e += 256) atomicAdd(&hist[dst[e] >> 8], 1);
    __syncthreads();
    for (int b = t; b < NBIN; b += 256) bh[b * BCNT_BLK + bid] = hist[b];
}

__global__ void __launch_bounds__(512) k_binscan(const int* __restrict__ bh,
                                                 int* __restrict__ binoff,
                                                 int* __restrict__ bincur) {
    __shared__ int sc[512];
    int t = threadIdx.x;
    int s = 0;
    if (t < NBIN) {
        const int* row = bh + t * BCNT_BLK;
        for (int k = 0; k < BCNT_BLK; k++) s += row[k];
    }
    sc[t] = s;
    __syncthreads();
    for (int off = 1; off < 512; off <<= 1) {
        int v = (t >= off) ? sc[t - off] : 0;
        __syncthreads();
        sc[t] += v;
        __syncthreads();
    }
    int excl = sc[t] - s;
    if (t <= NBIN) binoff[t] = excl;
    if (t < NBIN) bincur[t] = excl;
}

// ---------------- CSR build pass 1: coarse bin scatter ----------------
__global__ void __launch_bounds__(256) k_part1(const int* __restrict__ src,
                                               const int* __restrict__ dst,
                                               const float* __restrict__ w,
                                               int* __restrict__ bincur,
                                               int2* __restrict__ tmp_sw,
                                               unsigned char* __restrict__ tmp_dl) {
    __shared__ unsigned short sbin[P1_CHUNK];
    __shared__ unsigned short srnk[P1_CHUNK];
    __shared__ int hist[NBIN];
    __shared__ int base[NBIN];
    int t = threadIdx.x;
    int g0 = blockIdx.x * P1_CHUNK;
    int cn = N_EDGES - g0; if (cn > P1_CHUNK) cn = P1_CHUNK;
    for (int b = t; b < NBIN; b += 256) hist[b] = 0;
    __syncthreads();
    for (int j = t; j < cn; j += 256) {
        int d = dst[g0 + j];
        int b = d >> 8;
        sbin[j] = (unsigned short)b;
        srnk[j] = (unsigned short)atomicAdd(&hist[b], 1);
    }
    __syncthreads();
    for (int b = t; b < NBIN; b += 256) {
        int c = hist[b];
        base[b] = c ? atomicAdd(&bincur[b], c) : 0;
    }
    __syncthreads();
    for (int j = t; j < cn; j += 256) {
        int d = dst[g0 + j];
        int idx = base[sbin[j]] + srnk[j];
        tmp_sw[idx] = make_int2(src[g0 + j], __float_as_int(w[g0 + j]));
        tmp_dl[idx] = (unsigned char)(d & 255);
    }
}

// ---------------- CSR build pass 2: per-bin fine sort (LDS permute) + ptr ----------------
__global__ void __launch_bounds__(256) k_part2(const int2* __restrict__ tmp_sw,
                                               const unsigned char* __restrict__ tmp_dl,
                                               const int* __restrict__ binoff,
                                               int2* __restrict__ er,
                                               int* __restrict__ ptr) {
    __shared__ unsigned char sdl[MAXBIN];
    __shared__ unsigned short perm[MAXBIN];
    __shared__ int hist[256];
    __shared__ int cur[256];
    __shared__ int sc[256];
    int t = threadIdx.x, b = blockIdx.x;
    int nlo = b << 8;
    int e0 = binoff[b], e1 = binoff[b + 1];
    int cnt = e1 - e0;
    int stage = cnt < MAXBIN ? cnt : MAXBIN;
    hist[t] = 0;
    __syncthreads();
    for (int j = t; j < stage; j += 256) {
        unsigned char dl = tmp_dl[e0 + j];
        sdl[j] = dl;
        atomicAdd(&hist[dl], 1);
    }
    for (int j = stage + t; j < cnt; j += 256) atomicAdd(&hist[tmp_dl[e0 + j]], 1);
    __syncthreads();
    int v = hist[t];
    sc[t] = v;
    __syncthreads();
    for (int off = 1; off < 256; off <<= 1) {
        int u = (t >= off) ? sc[t - off] : 0;
        __syncthreads();
        sc[t] += u;
        __syncthreads();
    }
    int excl = sc[t] - v;
    cur[t] = excl;
    if (nlo + t < N_NODES) ptr[nlo + t] = e0 + excl;
    if (b == NBIN - 1 && t == 0) ptr[N_NODES] = N_EDGES;
    __syncthreads();
    for (int j = t; j < stage; j += 256) {
        int p = atomicAdd(&cur[sdl[j]], 1);
        perm[p] = (unsigned short)j;
    }
    __syncthreads();
    // overflow slow path (should never execute)
    for (int j = stage + t; j < cnt; j += 256) {
        int p = atomicAdd(&cur[tmp_dl[e0 + j]], 1);
        er[e0 + p] = tmp_sw[e0 + j];
    }
    for (int p = t; p < stage; p += 256) {
        er[e0 + p] = tmp_sw[e0 + perm[p]];
    }
}

// ---------------- fp16 conversion of pro_x ----------------
__global__ void k_half1(const float* __restrict__ x, __half* __restrict__ xh) {
    int i = blockIdx.x * blockDim.x + threadIdx.x;
    if (i < N_NODES * NFP) {
        int n = i / NFP, f = i - n * NFP;
        xh[n * ROW1 + f] = __float2half(x[i]);
    }
}

// ---------------- GINE layer 1 (33 -> 16) ----------------
__global__ void __launch_bounds__(256) k_gine1(
    const __half* __restrict__ xh, const int* __restrict__ ptr,
    const int2* __restrict__ er,
    const float* __restrict__ ew, const float* __restrict__ ebv,
    const float* __restrict__ epsp,
    const float* __restrict__ W1, const float* __restrict__ b1,
    const float* __restrict__ W2, const float* __restrict__ b2,
    float* __restrict__ z, float* __restrict__ part) {
    __shared__ float s_acc[32];
    int t = threadIdx.x;
    int wave = t >> 6, lane = t & 63;
    int e = lane >> 3, q = lane & 7;
    float4 ew4 = ((const float4*)ew)[q];
    float4 eb4 = ((const float4*)ebv)[q];
    float ew32 = ew[32], eb32 = ebv[32];
    float ep = 1.f + epsp[0];
    float rs = 0.f, rq = 0.f;
    for (int quad = blockIdx.x; quad < NQUAD; quad += GBLK) {
        int node = quad * 4 + wave;
        float a0 = 0, a1 = 0, a2 = 0, a3 = 0, a32 = 0;
        int e0 = ptr[node], e1 = ptr[node + 1];
        for (int i = e0 + e; i < e1; i += 8) {
            int2 ed = er[i];
            int s = ed.x; float wv = __int_as_float(ed.y);
            const __half* xr = xh + s * ROW1;
            uint2 raw = *(const uint2*)(xr + q * 4);
            float2 f01 = __half22float2(*(__half2*)&raw.x);
            float2 f23 = __half22float2(*(__half2*)&raw.y);
            a0 += fmaxf(f01.x + wv * ew4.x + eb4.x, 0.f);
            a1 += fmaxf(f01.y + wv * ew4.y + eb4.y, 0.f);
            a2 += fmaxf(f23.x + wv * ew4.z + eb4.z, 0.f);
            a3 += fmaxf(f23.y + wv * ew4.w + eb4.w, 0.f);
            if (q == 0) a32 += fmaxf(__half2float(xr[32]) + wv * ew32 + eb32, 0.f);
        }
        #pragma unroll
        for (int m = 8; m <= 32; m <<= 1) {
            a0 += __shfl_xor(a0, m); a1 += __shfl_xor(a1, m);
            a2 += __shfl_xor(a2, m); a3 += __shfl_xor(a3, m);
            a32 += __shfl_xor(a32, m);
        }
        const __half* xn = xh + node * ROW1;
        uint2 sraw = *(const uint2*)(xn + q * 4);
        float2 sf01 = __half22float2(*(__half2*)&sraw.x);
        float2 sf23 = __half22float2(*(__half2*)&sraw.y);
        float hq[4] = {ep * sf01.x + a0, ep * sf01.y + a1,
                       ep * sf23.x + a2, ep * sf23.y + a3};
        float xn32 = (q == 0) ? __half2float(xn[32]) : 0.f;
        float h32 = ep * xn32 + a32;
        int o = lane & 15;
        float tv = b1[o];
        #pragma unroll
        for (int ff = 0; ff < 32; ff++)
            tv += __shfl(hq[ff & 3], ff >> 2) * W1[ff * DIM + o];
        tv += __shfl(h32, 0) * W1[32 * DIM + o];
        tv = fmaxf(tv, 0.f);
        float zv = b2[o];
        #pragma unroll
        for (int ff = 0; ff < DIM; ff++) zv += __shfl(tv, ff) * W2[ff * DIM + o];
        zv = fmaxf(zv, 0.f);
        if (lane < DIM) {
            z[node * DIM + o] = zv;
            rs += zv; rq += zv * zv;
        }
    }
    if (t < 32) s_acc[t] = 0.f;
    __syncthreads();
    if (lane < DIM) { atomicAdd(&s_acc[lane], rs); atomicAdd(&s_acc[16 + lane], rq); }
    __syncthreads();
    if (t < 32) part[blockIdx.x * 32 + t] = s_acc[t];
}

// ---------------- GINE layers 2-5 (16 -> 16) ----------------
__global__ void __launch_bounds__(256) k_gine16(
    const __half* __restrict__ xh, const int* __restrict__ ptr,
    const int2* __restrict__ er,
    const float* __restrict__ ew, const float* __restrict__ ebv,
    const float* __restrict__ epsp,
    const float* __restrict__ W1, const float* __restrict__ b1,
    const float* __restrict__ W2, const float* __restrict__ b2,
    float* __restrict__ z, float* __restrict__ part) {
    __shared__ float s_acc[32];
    int t = threadIdx.x;
    int wave = t >> 6, lane = t & 63;
    int slot = lane >> 1, h = lane & 1;
    float4 ewlo = ((const float4*)ew)[h * 2];
    float4 ewhi = ((const float4*)ew)[h * 2 + 1];
    float4 eblo = ((const float4*)ebv)[h * 2];
    float4 ebhi = ((const float4*)ebv)[h * 2 + 1];
    float ep = 1.f + epsp[0];
    float rs = 0.f, rq = 0.f;
    for (int quad = blockIdx.x; quad < NQUAD; quad += GBLK) {
        int node = quad * 4 + wave;
        float a[8] = {0, 0, 0, 0, 0, 0, 0, 0};
        int e0 = ptr[node], e1 = ptr[node + 1];
        for (int i = e0 + slot; i < e1; i += 32) {
            int2 ed = er[i];
            int s = ed.x; float wv = __int_as_float(ed.y);
            uint4 raw = *(const uint4*)(xh + s * DIM + h * 8);
            float2 f01 = __half22float2(*(__half2*)&raw.x);
            float2 f23 = __half22float2(*(__half2*)&raw.y);
            float2 f45 = __half22float2(*(__half2*)&raw.z);
            float2 f67 = __half22float2(*(__half2*)&raw.w);
            a[0] += fmaxf(f01.x + wv * ewlo.x + eblo.x, 0.f);
            a[1] += fmaxf(f01.y + wv * ewlo.y + eblo.y, 0.f);
            a[2] += fmaxf(f23.x + wv * ewlo.z + eblo.z, 0.f);
            a[3] += fmaxf(f23.y + wv * ewlo.w + eblo.w, 0.f);
            a[4] += fmaxf(f45.x + wv * ewhi.x + ebhi.x, 0.f);
            a[5] += fmaxf(f45.y + wv * ewhi.y + ebhi.y, 0.f);
            a[6] += fmaxf(f67.x + wv * ewhi.z + ebhi.z, 0.f);
            a[7] += fmaxf(f67.y + wv * ewhi.w + ebhi.w, 0.f);
        }
        #pragma unroll
        for (int m = 2; m <= 32; m <<= 1) {
            #pragma unroll
            for (int j = 0; j < 8; j++) a[j] += __shfl_xor(a[j], m);
        }
        uint4 sraw = *(const uint4*)(xh + node * DIM + h * 8);
        float2 s01 = __half22float2(*(__half2*)&sraw.x);
        float2 s23 = __half22float2(*(__half2*)&sraw.y);
        float2 s45 = __half22float2(*(__half2*)&sraw.z);
        float2 s67 = __half22float2(*(__half2*)&sraw.w);
        float hq[8] = {ep * s01.x + a[0], ep * s01.y + a[1], ep * s23.x + a[2],
                       ep * s23.y + a[3], ep * s45.x + a[4], ep * s45.y + a[5],
                       ep * s67.x + a[6], ep * s67.y + a[7]};
        int f = lane & 15;
        float tv = b1[f];
        #pragma unroll
        for (int ff = 0; ff < DIM; ff++)
            tv += __shfl(hq[ff & 7], (ff >> 3) & 1) * W1[ff * DIM + f];
        tv = fmaxf(tv, 0.f);
        float zv = b2[f];
        #pragma unroll
        for (int ff = 0; ff < DIM; ff++) zv += __shfl(tv, ff) * W2[ff * DIM + f];
        zv = fmaxf(zv, 0.f);
        if (lane < DIM) {
            z[node * DIM + f] = zv;
            rs += zv; rq += zv * zv;
        }
    }
    if (t < 32) s_acc[t] = 0.f;
    __syncthreads();
    if (lane < DIM) { atomicAdd(&s_acc[lane], rs); atomicAdd(&s_acc[16 + lane], rq); }
    __syncthreads();
    if (t < 32) part[blockIdx.x * 32 + t] = s_acc[t];
}

// ---------------- reduce block partials -> bnstat[32] ----------------
__global__ void __launch_bounds__(1024) k_bnred(const float* __restrict__ part,
                                                float* __restrict__ bnstat) {
    __shared__ float red[1024];
    int t = threadIdx.x;
    int f = t & 31, g = t >> 5;
    float s = 0.f;
    for (int i = g; i < GBLK; i += 32) s += part[i * 32 + f];
    red[t] = s;
    __syncthreads();
    for (int off = 512; off >= 32; off >>= 1) {
        if (t < off) red[t] += red[t + off];
        __syncthreads();
    }
    if (t < 32) bnstat[t] = red[t];
}

// ---------------- BN normalize: fp32 z -> fp16 x ----------------
__global__ void k_norm(const float* __restrict__ z, __half* __restrict__ xh,
                       const float* __restrict__ bnstat, const float* __restrict__ gamma,
                       const float* __restrict__ beta) {
    int i = blockIdx.x * blockDim.x + threadIdx.x;
    int base = i * 4;
    if (base >= N_NODES * DIM) return;
    float4 zv = *(const float4*)(z + base);
    float zz[4] = {zv.x, zv.y, zv.z, zv.w};
    float out[4];
    int f0 = base & 15;
    const float invn = 1.f / (float)N_NODES;
    #pragma unroll
    for (int j = 0; j < 4; j++) {
        int f = f0 + j;
        float mu = bnstat[f] * invn;
        float var = bnstat[DIM + f] * invn - mu * mu;
        float sc = gamma[f] * rsqrtf(var + BN_EPSV);
        float sh = beta[f] - mu * sc;
        out[j] = zz[j] * sc + sh;
    }
    __half2* dst = (__half2*)(xh + base);
    dst[0] = __floats2half2_rn(out[0], out[1]);
    dst[1] = __floats2half2_rn(out[2], out[3]);
}

// ---------------- hierarchical pooling ----------------
__global__ void __launch_bounds__(256) k_pool(const __half* __restrict__ xh,
                                              const int* __restrict__ batch,
                                              float* __restrict__ gsum,
                                              float* __restrict__ gcnt) {
    __shared__ float lsum[BGR * DIM];
    __shared__ float lcnt[BGR];
    int t = threadIdx.x;
    for (int j = t; j < BGR * DIM; j += 256) lsum[j] = 0.f;
    if (t < BGR) lcnt[t] = 0.f;
    __syncthreads();
    int f = t & 15, r = t >> 4;
    int start = blockIdx.x * POOL_CHUNK;
    float acc = 0.f, cacc = 0.f;
    int cur = -1;
    for (int i = 0; i < POOL_CHUNK / 16; i++) {
        int n = start + r + i * 16;
        if (n >= N_NODES) break;
        int b = batch[n];
        if (b != cur) {
            if (cur >= 0) {
                atomicAdd(&lsum[cur * DIM + f], acc);
                if (f == 0) atomicAdd(&lcnt[cur], cacc);
            }
            cur = b; acc = 0.f; cacc = 0.f;
        }
        acc += __half2float(xh[n * DIM + f]);
        cacc += 1.f;
    }
    if (cur >= 0) {
        atomicAdd(&lsum[cur * DIM + f], acc);
        if (f == 0) atomicAdd(&lcnt[cur], cacc);
    }
    __syncthreads();
    for (int j = t; j < BGR * DIM; j += 256) {
        float v = lsum[j];
        if (v != 0.f) atomicAdd(&gsum[j], v);
    }
    if (t < BGR) {
        float v = lcnt[t];
        if (v != 0.f) atomicAdd(&gcnt[t], v);
    }
}

__global__ void k_xp(const float* __restrict__ gsum, const float* __restrict__ gcnt,
                     const float* __restrict__ w, const float* __restrict__ bias,
                     float* __restrict__ out) {
    int b = blockIdx.x;
    int e = threadIdx.x;
    float inv = 1.f / fmaxf(gcnt[b], 1.f);
    float acc = bias[e];
    #pragma unroll
    for (int f = 0; f < DIM; f++) acc += gsum[b * DIM + f] * inv * w[f * EMB + e];
    out[b * EMB + e] = fmaxf(acc, 0.f);
}

// ---------------- RNA ----------------
__global__ void __launch_bounds__(256) k_bucket(const int* __restrict__ tok, int L, int V,
                                                int* __restrict__ blist,
                                                int* __restrict__ bptr) {
    __shared__ int hist[65];
    __shared__ int cursor[65];
    int b = blockIdx.x, t = threadIdx.x;
    if (t < V) hist[t] = 0;
    __syncthreads();
    for (int l = t; l < L; l += 256) atomicAdd(&hist[tok[b * L + l]], 1);
    __syncthreads();
    if (t == 0) {
        int run = 0;
        for (int v = 0; v < V; v++) {
            cursor[v] = run;
            bptr[b * (V + 1) + v] = run;
            run += hist[v];
        }
        bptr[b * (V + 1) + V] = run;
    }
    __syncthreads();
    for (int l = t; l < L; l += 256) {
        int v = tok[b * L + l];
        int p = atomicAdd(&cursor[v], 1);
        blist[b * L + p] = l;
    }
}

__global__ void __launch_bounds__(256) k_wsum(const int* __restrict__ blist,
                                              const int* __restrict__ bptr,
                                              const float* __restrict__ cw,
                                              float* __restrict__ W, int L, int V) {
    int b = blockIdx.x, v = blockIdx.y;
    int t = threadIdx.x, o = t >> 3, k = t & 7;
    int s = bptr[b * (V + 1) + v], e = bptr[b * (V + 1) + v + 1];
    __shared__ int tk[256];
    const float* cwp = cw + o * (L * KS) + k;
    float acc = 0.f;
    for (int j0 = s; j0 < e; j0 += 256) {
        int lim = e - j0; if (lim > 256) lim = 256;
        __syncthreads();
        if (t < lim) tk[t] = blist[b * L + j0 + t];
        __syncthreads();
        for (int j = 0; j < lim; j++) acc += cwp[tk[j] * KS];
    }
    W[((b * NF + o) * V + v) * KS + k] = acc;
}

__global__ void k_y(const float* __restrict__ Wg, const float* __restrict__ Wl,
                    const float* __restrict__ emb1, const float* __restrict__ emb2,
                    const float* __restrict__ cb1, const float* __restrict__ cb2,
                    float* __restrict__ yg, float* __restrict__ yl) {
    int which = blockIdx.y;
    int bo = blockIdx.x;
    int b = bo >> 5, o = bo & 31;
    int t = threadIdx.x;  // 128
    const float* W = which ? Wl : Wg;
    const float* emb = which ? emb2 : emb1;
    const float* cb = which ? cb2 : cb1;
    float* y = which ? yl : yg;
    int V = which ? 65 : 5;
    __shared__ float Wsh[65 * KS];
    const float* Wrow = W + (b * NF + o) * V * KS;
    for (int j = t; j < V * KS; j += 128) Wsh[j] = Wrow[j];
    __syncthreads();
    if (t < OUTT) {
        float acc = cb[o];
        for (int v = 0; v < V; v++) {
            const float* ep = emb + v * EMB + t;
            #pragma unroll
            for (int k = 0; k < KS; k++) acc += Wsh[v * KS + k] * ep[k];
        }
        y[(b * NF + o) * OUTT + t] = acc;
    }
}

__global__ void k_fc(const float* __restrict__ yg, const float* __restrict__ yl,
                     const float* __restrict__ w, const float* __restrict__ bias,
                     float* __restrict__ xrg, float* __restrict__ xrl) {
    int b = blockIdx.x;
    int which = blockIdx.y;
    const float* y = which ? yl : yg;
    float* xr = which ? xrl : xrg;
    int e = threadIdx.x;  // 128
    __shared__ float ych[128];
    float acc = bias[e];
    for (int j0 = 0; j0 < FC_IN; j0 += 128) {
        __syncthreads();
        int lim = FC_IN - j0; if (lim > 128) lim = 128;
        if (e < lim) ych[e] = y[b * FC_IN + j0 + e];
        __syncthreads();
        for (int jj = 0; jj < lim; jj++) acc += ych[jj] * w[(j0 + jj) * EMB + e];
    }
    xr[b * EMB + e] = acc;
}

__global__ void k_comb(const float* __restrict__ xrg, const float* __restrict__ xrl,
                       float* __restrict__ out) {
    int i = blockIdx.x * blockDim.x + threadIdx.x;
    if (i < BGR * EMB) out[i] = 0.5f * (xrg[i] + xrl[i]);
}

extern "C" void kernel_launch(void* const* d_in, const int* in_sizes, int n_in,
                              void* d_out, int out_size, void* d_ws, size_t ws_size,
                              hipStream_t stream) {
    const float* pro_x = (const float*)d_in[0];
    const int* eidx = (const int*)d_in[1];
    const int* esrc = eidx;
    const int* edst = eidx + N_EDGES;
    const float* pw = (const float*)d_in[2];
    const int* batch = (const int*)d_in[3];
    const int* rg = (const int*)d_in[4];
    const int* rl = (const int*)d_in[5];
    const float* g1_w1 = (const float*)d_in[6];
    const float* g1_b1 = (const float*)d_in[7];
    const float* g1_w2 = (const float*)d_in[8];
    const float* g1_b2 = (const float*)d_in[9];
    const float* g1_ew = (const float*)d_in[10];
    const float* g1_eb = (const float*)d_in[11];
    const float* g1_eps = (const float*)d_in[12];
    const float* g_w1 = (const float*)d_in[13];
    const float* g_b1 = (const float*)d_in[14];
    const float* g_w2 = (const float*)d_in[15];
    const float* g_b2 = (const float*)d_in[16];
    const float* g_ew = (const float*)d_in[17];
    const float* g_eb = (const float*)d_in[18];
    const float* g_eps = (const float*)d_in[19];
    const float* bn_gamma = (const float*)d_in[20];
    const float* bn_beta = (const float*)d_in[21];
    const float* fc1_xp_w = (const float*)d_in[22];
    const float* fc1_xp_b = (const float*)d_in[23];
    const float* emb1 = (const float*)d_in[24];
    const float* emb2 = (const float*)d_in[25];
    const float* convr1_w = (const float*)d_in[26];
    const float* convr1_b = (const float*)d_in[27];
    const float* convr2_w = (const float*)d_in[28];
    const float* convr2_b = (const float*)d_in[29];
    const float* fcxr_w = (const float*)d_in[30];
    const float* fcxr_b = (const float*)d_in[31];
    float* out = (float*)d_out;

    // persistent buffers
    float* wsf = (float*)d_ws;
    int* ptr       = (int*)wsf;        wsf += 100128;
    int* binoff    = (int*)wsf;        wsf += 512;
    int* bincur    = (int*)wsf;        wsf += 512;
    int2* er       = (int2*)wsf;       wsf += 2 * N_EDGES;
    float* stats   = wsf;              wsf += 1280;
    // union region: CSR-build temporaries alias post-CSR buffers (stream-ordered)
    float* un = wsf;
    int2* tmp_sw          = (int2*)un;                       // 6.4M words
    unsigned char* tmp_dl = (unsigned char*)(un + 6400000);  // 800K words
    int* bh               = (int*)(un + 7200000);            // 200K words
    float* z     = un;                 // 1.6M
    __half* xh   = (__half*)(un + 1600000);   // 800K words
    __half* xh1  = (__half*)(un + 2400000);   // 1.8M words
    float* bpart = un + 4200000;       // 100K
    float* Wg    = un + 4300000;       // 82K
    float* Wl    = un + 4382000;       // 1.065M
    float* yg    = un + 5447000;       // 248K
    float* yl    = un + 5695000;       // 248K
    float* xrg   = un + 5943000;       // 8K
    float* xrl   = un + 5952000;       // 8K
    int* blg     = (int*)(un + 5961000);  // 192K
    int* bll     = (int*)(un + 6153000);  // 192K
    int* bpg     = (int*)(un + 6345000);
    int* bpl     = (int*)(un + 6346000);
    float* gsum   = stats;
    float* gcnt   = stats + 1024;
    float* bnstat = stats + 1088;

    hipMemsetAsync(stats, 0, 1280 * sizeof(float), stream);

    // CSR build (binned two-phase, no contended global atomics on hot paths)
    k_bincnt<<<BCNT_BLK, 256, 0, stream>>>(edst, bh);
    k_binscan<<<1, 512, 0, stream>>>(bh, binoff, bincur);
    k_part1<<<P1_BLOCKS, 256, 0, stream>>>(esrc, edst, pw, bincur, tmp_sw, tmp_dl);
    k_part2<<<NBIN, 256, 0, stream>>>(tmp_sw, tmp_dl, binoff, er, ptr);

    // pro_x -> fp16 padded rows (after CSR: xh1 aliases tmp region)
    k_half1<<<(N_NODES * NFP + 255) / 256, 256, 0, stream>>>(pro_x, xh1);

    // RNA branch
    k_bucket<<<BGR, 256, 0, stream>>>(rg, MAXLEN, 5, blg, bpg);
    k_bucket<<<BGR, 256, 0, stream>>>(rl, LOCLEN, 65, bll, bpl);
    k_wsum<<<dim3(BGR, 5), 256, 0, stream>>>(blg, bpg, convr1_w, Wg, MAXLEN, 5);
    k_wsum<<<dim3(BGR, 65), 256, 0, stream>>>(bll, bpl, convr2_w, Wl, LOCLEN, 65);
    k_y<<<dim3(BGR * NF, 2), 128, 0, stream>>>(Wg, Wl, emb1, emb2, convr1_b, convr2_b, yg, yl);
    k_fc<<<dim3(BGR, 2), 128, 0, stream>>>(yg, yl, fcxr_w, fcxr_b, xrg, xrl);
    k_comb<<<(BGR * EMB + 255) / 256, 256, 0, stream>>>(xrg, xrl, out);

    // GNN stack
    int nblocks = (N_NODES * DIM / 4 + 255) / 256;
    k_gine1<<<GBLK, 256, 0, stream>>>(xh1, ptr, er, g1_ew, g1_eb, g1_eps,
                                      g1_w1, g1_b1, g1_w2, g1_b2, z, bpart);
    k_bnred<<<1, 1024, 0, stream>>>(bpart, bnstat);
    k_norm<<<nblocks, 256, 0, stream>>>(z, xh, bnstat, bn_gamma, bn_beta);
    for (int i = 0; i < 4; i++) {
        k_gine16<<<GBLK, 256, 0, stream>>>(xh, ptr, er,
                                           g_ew + i * DIM, g_eb + i * DIM, g_eps + i,
                                           g_w1 + i * DIM * DIM, g_b1 + i * DIM,
                                           g_w2 + i * DIM * DIM, g_b2 + i * DIM,
                                           z, bpart);
        k_bnred<<<1, 1024, 0, stream>>>(bpart, bnstat + (i + 1) * 32);
        k_norm<<<nblocks, 256, 0, stream>>>(z, xh, bnstat + (i + 1) * 32,
                                            bn_gamma + (i + 1) * DIM, bn_beta + (i + 1) * DIM);
    }
    k_pool<<<(N_NODES + POOL_CHUNK - 1) / POOL_CHUNK, 256, 0, stream>>>(xh, batch, gsum, gcnt);
    k_xp<<<BGR, EMB, 0, stream>>>(gsum, gcnt, fc1_xp_w, fc1_xp_b, out + BGR * EMB);
}

// Round 8
// 1172.554 us; speedup vs baseline: 3.3528x; 1.1237x over previous
//
#include <hip/hip_runtime.h>
#include <hip/hip_fp16.h>

#define N_NODES 100000
#define N_EDGES 3200000
#define BGR 64
#define DIM 16
#define NFP 33
#define ROW1 32   // half-row for pro_x main features (64B = 1 line); feature 32 separate
#define EMB 128
#define MAXLEN 3000
#define LOCLEN 2998
#define NF 32
#define KS 8
#define OUTT 121
#define FC_IN 3872
#define BN_EPSV 1e-5f
#define POOL_CHUNK 2048
#define NQUAD 25000      // N_NODES / 4
#define GBLK 3125        // gine grid
// binned CSR build
#define NBIN 391         // ceil(100000/256), 256 nodes per bin
#define BCNT_BLK 512
#define P1_CHUNK 4096
#define P1_BLOCKS 782
#define MAXBIN 9088
// fc K-split
#define NKC 32
#define KCH 121          // FC_IN / NKC

// ---------------- CSR build: bin counts ----------------
__global__ void __launch_bounds__(256) k_bincnt(const int* __restrict__ dst,
                                                int* __restrict__ bh) {
    __shared__ int hist[NBIN];
    int t = threadIdx.x, bid = blockIdx.x;
    for (int b = t; b < NBIN; b += 256) hist[b] = 0;
    __syncthreads();
    int e0 = bid * (N_EDGES / BCNT_BLK);
    int e1 = e0 + (N_EDGES / BCNT_BLK);
    for (int e = e0 + t; e < e1; e += 256) atomicAdd(&hist[dst[e] >> 8], 1);
    __syncthreads();
    for (int b = t; b < NBIN; b += 256) bh[b * BCNT_BLK + bid] = hist[b];
}

__global__ void __launch_bounds__(512) k_binscan(const int* __restrict__ bh,
                                                 int* __restrict__ binoff,
                                                 int* __restrict__ bincur) {
    __shared__ int sc[512];
    int t = threadIdx.x;
    int s = 0;
    if (t < NBIN) {
        const int* row = bh + t * BCNT_BLK;
        for (int k = 0; k < BCNT_BLK; k++) s += row[k];
    }
    sc[t] = s;
    __syncthreads();
    for (int off = 1; off < 512; off <<= 1) {
        int v = (t >= off) ? sc[t - off] : 0;
        __syncthreads();
        sc[t] += v;
        __syncthreads();
    }
    int excl = sc[t] - s;
    if (t <= NBIN) binoff[t] = excl;
    if (t < NBIN) bincur[t] = excl;
}

// ---------------- CSR build pass 1: coarse bin scatter ----------------
__global__ void __launch_bounds__(256) k_part1(const int* __restrict__ src,
                                               const int* __restrict__ dst,
                                               const float* __restrict__ w,
                                               int* __restrict__ bincur,
                                               int2* __restrict__ tmp_sw,
                                               unsigned char* __restrict__ tmp_dl) {
    __shared__ unsigned short sbin[P1_CHUNK];
    __shared__ unsigned short srnk[P1_CHUNK];
    __shared__ int hist[NBIN];
    __shared__ int base[NBIN];
    int t = threadIdx.x;
    int g0 = blockIdx.x * P1_CHUNK;
    int cn = N_EDGES - g0; if (cn > P1_CHUNK) cn = P1_CHUNK;
    for (int b = t; b < NBIN; b += 256) hist[b] = 0;
    __syncthreads();
    for (int j = t; j < cn; j += 256) {
        int d = dst[g0 + j];
        int b = d >> 8;
        sbin[j] = (unsigned short)b;
        srnk[j] = (unsigned short)atomicAdd(&hist[b], 1);
    }
    __syncthreads();
    for (int b = t; b < NBIN; b += 256) {
        int c = hist[b];
        base[b] = c ? atomicAdd(&bincur[b], c) : 0;
    }
    __syncthreads();
    for (int j = t; j < cn; j += 256) {
        int d = dst[g0 + j];
        int idx = base[sbin[j]] + srnk[j];
        tmp_sw[idx] = make_int2(src[g0 + j], __float_as_int(w[g0 + j]));
        tmp_dl[idx] = (unsigned char)(d & 255);
    }
}

// ---------------- CSR build pass 2: per-bin fine sort + ptr ----------------
__global__ void __launch_bounds__(256) k_part2(const int2* __restrict__ tmp_sw,
                                               const unsigned char* __restrict__ tmp_dl,
                                               const int* __restrict__ binoff,
                                               int2* __restrict__ er,
                                               int* __restrict__ ptr) {
    __shared__ unsigned char sdl[MAXBIN];
    __shared__ unsigned short perm[MAXBIN];
    __shared__ int hist[256];
    __shared__ int cur[256];
    __shared__ int sc[256];
    int t = threadIdx.x, b = blockIdx.x;
    int nlo = b << 8;
    int e0 = binoff[b], e1 = binoff[b + 1];
    int cnt = e1 - e0;
    int stage = cnt < MAXBIN ? cnt : MAXBIN;
    hist[t] = 0;
    __syncthreads();
    for (int j = t; j < stage; j += 256) {
        unsigned char dl = tmp_dl[e0 + j];
        sdl[j] = dl;
        atomicAdd(&hist[dl], 1);
    }
    for (int j = stage + t; j < cnt; j += 256) atomicAdd(&hist[tmp_dl[e0 + j]], 1);
    __syncthreads();
    int v = hist[t];
    sc[t] = v;
    __syncthreads();
    for (int off = 1; off < 256; off <<= 1) {
        int u = (t >= off) ? sc[t - off] : 0;
        __syncthreads();
        sc[t] += u;
        __syncthreads();
    }
    int excl = sc[t] - v;
    cur[t] = excl;
    if (nlo + t < N_NODES) ptr[nlo + t] = e0 + excl;
    if (b == NBIN - 1 && t == 0) ptr[N_NODES] = N_EDGES;
    __syncthreads();
    for (int j = t; j < stage; j += 256) {
        int p = atomicAdd(&cur[sdl[j]], 1);
        perm[p] = (unsigned short)j;
    }
    __syncthreads();
    for (int j = stage + t; j < cnt; j += 256) {
        int p = atomicAdd(&cur[tmp_dl[e0 + j]], 1);
        er[e0 + p] = tmp_sw[e0 + j];
    }
    for (int p = t; p < stage; p += 256) {
        er[e0 + p] = tmp_sw[e0 + perm[p]];
    }
}

// ---------------- fp16 conversion of pro_x: 32-feature rows + separate f32 col ----------------
__global__ void k_half1(const float* __restrict__ x, __half* __restrict__ xh,
                        __half* __restrict__ xh32) {
    int i = blockIdx.x * blockDim.x + threadIdx.x;
    if (i < N_NODES * NFP) {
        int n = i / NFP, f = i - n * NFP;
        __half v = __float2half(x[i]);
        if (f < 32) xh[n * ROW1 + f] = v;
        else xh32[n] = v;
    }
}

// ---------------- GINE layer 1 (33 -> 16) ----------------
__global__ void __launch_bounds__(256) k_gine1(
    const __half* __restrict__ xh, const __half* __restrict__ xh32,
    const int* __restrict__ ptr, const int2* __restrict__ er,
    const float* __restrict__ ew, const float* __restrict__ ebv,
    const float* __restrict__ epsp,
    const float* __restrict__ W1, const float* __restrict__ b1,
    const float* __restrict__ W2, const float* __restrict__ b2,
    float* __restrict__ z, float* __restrict__ part) {
    __shared__ float s_acc[32];
    int t = threadIdx.x;
    int wave = t >> 6, lane = t & 63;
    int e = lane >> 3, q = lane & 7;
    float4 ew4 = ((const float4*)ew)[q];
    float4 eb4 = ((const float4*)ebv)[q];
    float ew32 = ew[32], eb32 = ebv[32];
    float ep = 1.f + epsp[0];
    float rs = 0.f, rq = 0.f;
    for (int quad = blockIdx.x; quad < NQUAD; quad += GBLK) {
        int node = quad * 4 + wave;
        float a0 = 0, a1 = 0, a2 = 0, a3 = 0, a32 = 0;
        int e0 = ptr[node], e1 = ptr[node + 1];
        for (int i = e0 + e; i < e1; i += 8) {
            int2 ed = er[i];
            int s = ed.x; float wv = __int_as_float(ed.y);
            uint2 raw = *(const uint2*)(xh + s * ROW1 + q * 4);
            float2 f01 = __half22float2(*(__half2*)&raw.x);
            float2 f23 = __half22float2(*(__half2*)&raw.y);
            a0 += fmaxf(f01.x + wv * ew4.x + eb4.x, 0.f);
            a1 += fmaxf(f01.y + wv * ew4.y + eb4.y, 0.f);
            a2 += fmaxf(f23.x + wv * ew4.z + eb4.z, 0.f);
            a3 += fmaxf(f23.y + wv * ew4.w + eb4.w, 0.f);
            if (q == 0) a32 += fmaxf(__half2float(xh32[s]) + wv * ew32 + eb32, 0.f);
        }
        #pragma unroll
        for (int m = 8; m <= 32; m <<= 1) {
            a0 += __shfl_xor(a0, m); a1 += __shfl_xor(a1, m);
            a2 += __shfl_xor(a2, m); a3 += __shfl_xor(a3, m);
            a32 += __shfl_xor(a32, m);
        }
        uint2 sraw = *(const uint2*)(xh + node * ROW1 + q * 4);
        float2 sf01 = __half22float2(*(__half2*)&sraw.x);
        float2 sf23 = __half22float2(*(__half2*)&sraw.y);
        float hq[4] = {ep * sf01.x + a0, ep * sf01.y + a1,
                       ep * sf23.x + a2, ep * sf23.y + a3};
        float xn32 = (q == 0) ? __half2float(xh32[node]) : 0.f;
        float h32 = ep * xn32 + a32;
        int o = lane & 15;
        float tv = b1[o];
        #pragma unroll
        for (int ff = 0; ff < 32; ff++)
            tv += __shfl(hq[ff & 3], ff >> 2) * W1[ff * DIM + o];
        tv += __shfl(h32, 0) * W1[32 * DIM + o];
        tv = fmaxf(tv, 0.f);
        float zv = b2[o];
        #pragma unroll
        for (int ff = 0; ff < DIM; ff++) zv += __shfl(tv, ff) * W2[ff * DIM + o];
        zv = fmaxf(zv, 0.f);
        if (lane < DIM) {
            z[node * DIM + o] = zv;
            rs += zv; rq += zv * zv;
        }
    }
    if (t < 32) s_acc[t] = 0.f;
    __syncthreads();
    if (lane < DIM) { atomicAdd(&s_acc[lane], rs); atomicAdd(&s_acc[16 + lane], rq); }
    __syncthreads();
    if (t < 32) part[blockIdx.x * 32 + t] = s_acc[t];
}

// ---------------- GINE layers 2-5 (16 -> 16) ----------------
__global__ void __launch_bounds__(256) k_gine16(
    const __half* __restrict__ xh, const int* __restrict__ ptr,
    const int2* __restrict__ er,
    const float* __restrict__ ew, const float* __restrict__ ebv,
    const float* __restrict__ epsp,
    const float* __restrict__ W1, const float* __restrict__ b1,
    const float* __restrict__ W2, const float* __restrict__ b2,
    float* __restrict__ z, float* __restrict__ part) {
    __shared__ float s_acc[32];
    int t = threadIdx.x;
    int wave = t >> 6, lane = t & 63;
    int slot = lane >> 1, h = lane & 1;
    float4 ewlo = ((const float4*)ew)[h * 2];
    float4 ewhi = ((const float4*)ew)[h * 2 + 1];
    float4 eblo = ((const float4*)ebv)[h * 2];
    float4 ebhi = ((const float4*)ebv)[h * 2 + 1];
    float ep = 1.f + epsp[0];
    float rs = 0.f, rq = 0.f;
    for (int quad = blockIdx.x; quad < NQUAD; quad += GBLK) {
        int node = quad * 4 + wave;
        float a[8] = {0, 0, 0, 0, 0, 0, 0, 0};
        int e0 = ptr[node], e1 = ptr[node + 1];
        for (int i = e0 + slot; i < e1; i += 32) {
            int2 ed = er[i];
            int s = ed.x; float wv = __int_as_float(ed.y);
            uint4 raw = *(const uint4*)(xh + s * DIM + h * 8);
            float2 f01 = __half22float2(*(__half2*)&raw.x);
            float2 f23 = __half22float2(*(__half2*)&raw.y);
            float2 f45 = __half22float2(*(__half2*)&raw.z);
            float2 f67 = __half22float2(*(__half2*)&raw.w);
            a[0] += fmaxf(f01.x + wv * ewlo.x + eblo.x, 0.f);
            a[1] += fmaxf(f01.y + wv * ewlo.y + eblo.y, 0.f);
            a[2] += fmaxf(f23.x + wv * ewlo.z + eblo.z, 0.f);
            a[3] += fmaxf(f23.y + wv * ewlo.w + eblo.w, 0.f);
            a[4] += fmaxf(f45.x + wv * ewhi.x + ebhi.x, 0.f);
            a[5] += fmaxf(f45.y + wv * ewhi.y + ebhi.y, 0.f);
            a[6] += fmaxf(f67.x + wv * ewhi.z + ebhi.z, 0.f);
            a[7] += fmaxf(f67.y + wv * ewhi.w + ebhi.w, 0.f);
        }
        #pragma unroll
        for (int m = 2; m <= 32; m <<= 1) {
            #pragma unroll
            for (int j = 0; j < 8; j++) a[j] += __shfl_xor(a[j], m);
        }
        uint4 sraw = *(const uint4*)(xh + node * DIM + h * 8);
        float2 s01 = __half22float2(*(__half2*)&sraw.x);
        float2 s23 = __half22float2(*(__half2*)&sraw.y);
        float2 s45 = __half22float2(*(__half2*)&sraw.z);
        float2 s67 = __half22float2(*(__half2*)&sraw.w);
        float hq[8] = {ep * s01.x + a[0], ep * s01.y + a[1], ep * s23.x + a[2],
                       ep * s23.y + a[3], ep * s45.x + a[4], ep * s45.y + a[5],
                       ep * s67.x + a[6], ep * s67.y + a[7]};
        int f = lane & 15;
        float tv = b1[f];
        #pragma unroll
        for (int ff = 0; ff < DIM; ff++)
            tv += __shfl(hq[ff & 7], (ff >> 3) & 1) * W1[ff * DIM + f];
        tv = fmaxf(tv, 0.f);
        float zv = b2[f];
        #pragma unroll
        for (int ff = 0; ff < DIM; ff++) zv += __shfl(tv, ff) * W2[ff * DIM + f];
        zv = fmaxf(zv, 0.f);
        if (lane < DIM) {
            z[node * DIM + f] = zv;
            rs += zv; rq += zv * zv;
        }
    }
    if (t < 32) s_acc[t] = 0.f;
    __syncthreads();
    if (lane < DIM) { atomicAdd(&s_acc[lane], rs); atomicAdd(&s_acc[16 + lane], rq); }
    __syncthreads();
    if (t < 32) part[blockIdx.x * 32 + t] = s_acc[t];
}

// ---------------- reduce block partials -> bnstat[32] ----------------
__global__ void __launch_bounds__(1024) k_bnred(const float* __restrict__ part,
                                                float* __restrict__ bnstat) {
    __shared__ float red[1024];
    int t = threadIdx.x;
    int f = t & 31, g = t >> 5;
    float s = 0.f;
    for (int i = g; i < GBLK; i += 32) s += part[i * 32 + f];
    red[t] = s;
    __syncthreads();
    for (int off = 512; off >= 32; off >>= 1) {
        if (t < off) red[t] += red[t + off];
        __syncthreads();
    }
    if (t < 32) bnstat[t] = red[t];
}

// ---------------- BN normalize: fp32 z -> fp16 x ----------------
__global__ void k_norm(const float* __restrict__ z, __half* __restrict__ xh,
                       const float* __restrict__ bnstat, const float* __restrict__ gamma,
                       const float* __restrict__ beta) {
    int i = blockIdx.x * blockDim.x + threadIdx.x;
    int base = i * 4;
    if (base >= N_NODES * DIM) return;
    float4 zv = *(const float4*)(z + base);
    float zz[4] = {zv.x, zv.y, zv.z, zv.w};
    float out[4];
    int f0 = base & 15;
    const float invn = 1.f / (float)N_NODES;
    #pragma unroll
    for (int j = 0; j < 4; j++) {
        int f = f0 + j;
        float mu = bnstat[f] * invn;
        float var = bnstat[DIM + f] * invn - mu * mu;
        float sc = gamma[f] * rsqrtf(var + BN_EPSV);
        float sh = beta[f] - mu * sc;
        out[j] = zz[j] * sc + sh;
    }
    __half2* dst = (__half2*)(xh + base);
    dst[0] = __floats2half2_rn(out[0], out[1]);
    dst[1] = __floats2half2_rn(out[2], out[3]);
}

// ---------------- hierarchical pooling ----------------
__global__ void __launch_bounds__(256) k_pool(const __half* __restrict__ xh,
                                              const int* __restrict__ batch,
                                              float* __restrict__ gsum,
                                              float* __restrict__ gcnt) {
    __shared__ float lsum[BGR * DIM];
    __shared__ float lcnt[BGR];
    int t = threadIdx.x;
    for (int j = t; j < BGR * DIM; j += 256) lsum[j] = 0.f;
    if (t < BGR) lcnt[t] = 0.f;
    __syncthreads();
    int f = t & 15, r = t >> 4;
    int start = blockIdx.x * POOL_CHUNK;
    float acc = 0.f, cacc = 0.f;
    int cur = -1;
    for (int i = 0; i < POOL_CHUNK / 16; i++) {
        int n = start + r + i * 16;
        if (n >= N_NODES) break;
        int b = batch[n];
        if (b != cur) {
            if (cur >= 0) {
                atomicAdd(&lsum[cur * DIM + f], acc);
                if (f == 0) atomicAdd(&lcnt[cur], cacc);
            }
            cur = b; acc = 0.f; cacc = 0.f;
        }
        acc += __half2float(xh[n * DIM + f]);
        cacc += 1.f;
    }
    if (cur >= 0) {
        atomicAdd(&lsum[cur * DIM + f], acc);
        if (f == 0) atomicAdd(&lcnt[cur], cacc);
    }
    __syncthreads();
    for (int j = t; j < BGR * DIM; j += 256) {
        float v = lsum[j];
        if (v != 0.f) atomicAdd(&gsum[j], v);
    }
    if (t < BGR) {
        float v = lcnt[t];
        if (v != 0.f) atomicAdd(&gcnt[t], v);
    }
}

__global__ void k_xp(const float* __restrict__ gsum, const float* __restrict__ gcnt,
                     const float* __restrict__ w, const float* __restrict__ bias,
                     float* __restrict__ out) {
    int b = blockIdx.x;
    int e = threadIdx.x;
    float inv = 1.f / fmaxf(gcnt[b], 1.f);
    float acc = bias[e];
    #pragma unroll
    for (int f = 0; f < DIM; f++) acc += gsum[b * DIM + f] * inv * w[f * EMB + e];
    out[b * EMB + e] = fmaxf(acc, 0.f);
}

// ---------------- RNA ----------------
__global__ void __launch_bounds__(256) k_bucket(const int* __restrict__ tok, int L, int V,
                                                int* __restrict__ blist,
                                                int* __restrict__ bptr) {
    __shared__ int hist[65];
    __shared__ int cursor[65];
    int b = blockIdx.x, t = threadIdx.x;
    if (t < V) hist[t] = 0;
    __syncthreads();
    for (int l = t; l < L; l += 256) atomicAdd(&hist[tok[b * L + l]], 1);
    __syncthreads();
    if (t == 0) {
        int run = 0;
        for (int v = 0; v < V; v++) {
            cursor[v] = run;
            bptr[b * (V + 1) + v] = run;
            run += hist[v];
        }
        bptr[b * (V + 1) + V] = run;
    }
    __syncthreads();
    for (int l = t; l < L; l += 256) {
        int v = tok[b * L + l];
        int p = atomicAdd(&cursor[v], 1);
        blist[b * L + p] = l;
    }
}

__global__ void __launch_bounds__(256) k_wsum(const int* __restrict__ blist,
                                              const int* __restrict__ bptr,
                                              const float* __restrict__ cw,
                                              float* __restrict__ W, int L, int V) {
    int b = blockIdx.x, v = blockIdx.y;
    int t = threadIdx.x, o = t >> 3, k = t & 7;
    int s = bptr[b * (V + 1) + v], e = bptr[b * (V + 1) + v + 1];
    __shared__ int tk[256];
    const float* cwp = cw + o * (L * KS) + k;
    float acc = 0.f;
    for (int j0 = s; j0 < e; j0 += 256) {
        int lim = e - j0; if (lim > 256) lim = 256;
        __syncthreads();
        if (t < lim) tk[t] = blist[b * L + j0 + t];
        __syncthreads();
        for (int j = 0; j < lim; j++) acc += cwp[tk[j] * KS];
    }
    W[((b * NF + o) * V + v) * KS + k] = acc;
}

__global__ void k_y(const float* __restrict__ Wg, const float* __restrict__ Wl,
                    const float* __restrict__ emb1, const float* __restrict__ emb2,
                    const float* __restrict__ cb1, const float* __restrict__ cb2,
                    float* __restrict__ yg, float* __restrict__ yl) {
    int which = blockIdx.y;
    int bo = blockIdx.x;
    int b = bo >> 5, o = bo & 31;
    int t = threadIdx.x;  // 128
    const float* W = which ? Wl : Wg;
    const float* emb = which ? emb2 : emb1;
    const float* cb = which ? cb2 : cb1;
    float* y = which ? yl : yg;
    int V = which ? 65 : 5;
    __shared__ float Wsh[65 * KS];
    const float* Wrow = W + (b * NF + o) * V * KS;
    for (int j = t; j < V * KS; j += 128) Wsh[j] = Wrow[j];
    __syncthreads();
    if (t < OUTT) {
        float acc = cb[o];
        for (int v = 0; v < V; v++) {
            const float* ep = emb + v * EMB + t;
            #pragma unroll
            for (int k = 0; k < KS; k++) acc += Wsh[v * KS + k] * ep[k];
        }
        y[(b * NF + o) * OUTT + t] = acc;
    }
}

// ---------------- fc: K-split partial GEMV + reduce ----------------
__global__ void __launch_bounds__(128) k_fcpart(const float* __restrict__ yg,
                                                const float* __restrict__ yl,
                                                const float* __restrict__ w,
                                                float* __restrict__ partial) {
    int b = blockIdx.x, which = blockIdx.y, kc = blockIdx.z;
    const float* y = which ? yl : yg;
    int e = threadIdx.x;
    __shared__ float ych[KCH];
    int j0 = kc * KCH;
    if (e < KCH) ych[e] = y[b * FC_IN + j0 + e];
    __syncthreads();
    float acc = 0.f;
    #pragma unroll 4
    for (int jj = 0; jj < KCH; jj++) acc += ych[jj] * w[(j0 + jj) * EMB + e];
    partial[((which * BGR + b) * NKC + kc) * EMB + e] = acc;
}

__global__ void k_fcred(const float* __restrict__ partial, const float* __restrict__ bias,
                        float* __restrict__ xrg, float* __restrict__ xrl) {
    int b = blockIdx.x, which = blockIdx.y;
    int e = threadIdx.x;
    const float* p = partial + (which * BGR + b) * NKC * EMB + e;
    float acc = bias[e];
    #pragma unroll
    for (int k = 0; k < NKC; k++) acc += p[k * EMB];
    (which ? xrl : xrg)[b * EMB + e] = acc;
}

__global__ void k_comb(const float* __restrict__ xrg, const float* __restrict__ xrl,
                       float* __restrict__ out) {
    int i = blockIdx.x * blockDim.x + threadIdx.x;
    if (i < BGR * EMB) out[i] = 0.5f * (xrg[i] + xrl[i]);
}

extern "C" void kernel_launch(void* const* d_in, const int* in_sizes, int n_in,
                              void* d_out, int out_size, void* d_ws, size_t ws_size,
                              hipStream_t stream) {
    const float* pro_x = (const float*)d_in[0];
    const int* eidx = (const int*)d_in[1];
    const int* esrc = eidx;
    const int* edst = eidx + N_EDGES;
    const float* pw = (const float*)d_in[2];
    const int* batch = (const int*)d_in[3];
    const int* rg = (const int*)d_in[4];
    const int* rl = (const int*)d_in[5];
    const float* g1_w1 = (const float*)d_in[6];
    const float* g1_b1 = (const float*)d_in[7];
    const float* g1_w2 = (const float*)d_in[8];
    const float* g1_b2 = (const float*)d_in[9];
    const float* g1_ew = (const float*)d_in[10];
    const float* g1_eb = (const float*)d_in[11];
    const float* g1_eps = (const float*)d_in[12];
    const float* g_w1 = (const float*)d_in[13];
    const float* g_b1 = (const float*)d_in[14];
    const float* g_w2 = (const float*)d_in[15];
    const float* g_b2 = (const float*)d_in[16];
    const float* g_ew = (const float*)d_in[17];
    const float* g_eb = (const float*)d_in[18];
    const float* g_eps = (const float*)d_in[19];
    const float* bn_gamma = (const float*)d_in[20];
    const float* bn_beta = (const float*)d_in[21];
    const float* fc1_xp_w = (const float*)d_in[22];
    const float* fc1_xp_b = (const float*)d_in[23];
    const float* emb1 = (const float*)d_in[24];
    const float* emb2 = (const float*)d_in[25];
    const float* convr1_w = (const float*)d_in[26];
    const float* convr1_b = (const float*)d_in[27];
    const float* convr2_w = (const float*)d_in[28];
    const float* convr2_b = (const float*)d_in[29];
    const float* fcxr_w = (const float*)d_in[30];
    const float* fcxr_b = (const float*)d_in[31];
    float* out = (float*)d_out;

    // persistent buffers
    float* wsf = (float*)d_ws;
    int* ptr       = (int*)wsf;        wsf += 100128;
    int* binoff    = (int*)wsf;        wsf += 512;
    int* bincur    = (int*)wsf;        wsf += 512;
    int2* er       = (int2*)wsf;       wsf += 2 * N_EDGES;
    float* stats   = wsf;              wsf += 1280;
    // union region: CSR-build temporaries alias post-CSR buffers (stream-ordered)
    float* un = wsf;
    int2* tmp_sw          = (int2*)un;                       // words [0, 6.4M)
    unsigned char* tmp_dl = (unsigned char*)(un + 6400000);  // [6.4M, 7.2M)
    int* bh               = (int*)(un + 7200000);            // [7.2M, 7.4M)
    float* z     = un;                        // 1.6M
    __half* xh   = (__half*)(un + 1600000);   // 800K words
    __half* xh1  = (__half*)(un + 2400000);   // 1.6M words
    __half* xh32 = (__half*)(un + 4000000);   // 50K words
    float* bpart = un + 4100000;              // 100K
    float* Wg    = un + 4300000;              // 82K
    float* Wl    = un + 4382000;              // 1.065M
    float* yg    = un + 5447000;              // 248K
    float* yl    = un + 5695000;              // 248K
    float* xrg   = un + 5943000;
    float* xrl   = un + 5952000;
    int* blg     = (int*)(un + 5961000);      // 192K
    int* bll     = (int*)(un + 6153000);      // 192K
    int* bpg     = (int*)(un + 6345000);
    int* bpl     = (int*)(un + 6346000);
    float* fcpart = un + 6360000;             // 524288 words (ends 6884288 < 7.2M)
    float* gsum   = stats;
    float* gcnt   = stats + 1024;
    float* bnstat = stats + 1088;

    hipMemsetAsync(stats, 0, 1280 * sizeof(float), stream);

    // CSR build (binned two-phase)
    k_bincnt<<<BCNT_BLK, 256, 0, stream>>>(edst, bh);
    k_binscan<<<1, 512, 0, stream>>>(bh, binoff, bincur);
    k_part1<<<P1_BLOCKS, 256, 0, stream>>>(esrc, edst, pw, bincur, tmp_sw, tmp_dl);
    k_part2<<<NBIN, 256, 0, stream>>>(tmp_sw, tmp_dl, binoff, er, ptr);

    // pro_x -> fp16 rows (after CSR: xh1 aliases tmp region)
    k_half1<<<(N_NODES * NFP + 255) / 256, 256, 0, stream>>>(pro_x, xh1, xh32);

    // RNA branch
    k_bucket<<<BGR, 256, 0, stream>>>(rg, MAXLEN, 5, blg, bpg);
    k_bucket<<<BGR, 256, 0, stream>>>(rl, LOCLEN, 65, bll, bpl);
    k_wsum<<<dim3(BGR, 5), 256, 0, stream>>>(blg, bpg, convr1_w, Wg, MAXLEN, 5);
    k_wsum<<<dim3(BGR, 65), 256, 0, stream>>>(bll, bpl, convr2_w, Wl, LOCLEN, 65);
    k_y<<<dim3(BGR * NF, 2), 128, 0, stream>>>(Wg, Wl, emb1, emb2, convr1_b, convr2_b, yg, yl);
    k_fcpart<<<dim3(BGR, 2, NKC), 128, 0, stream>>>(yg, yl, fcxr_w, fcpart);
    k_fcred<<<dim3(BGR, 2), 128, 0, stream>>>(fcpart, fcxr_b, xrg, xrl);
    k_comb<<<(BGR * EMB + 255) / 256, 256, 0, stream>>>(xrg, xrl, out);

    // GNN stack
    int nblocks = (N_NODES * DIM / 4 + 255) / 256;
    k_gine1<<<GBLK, 256, 0, stream>>>(xh1, xh32, ptr, er, g1_ew, g1_eb, g1_eps,
                                      g1_w1, g1_b1, g1_w2, g1_b2, z, bpart);
    k_bnred<<<1, 1024, 0, stream>>>(bpart, bnstat);
    k_norm<<<nblocks, 256, 0, stream>>>(z, xh, bnstat, bn_gamma, bn_beta);
    for (int i = 0; i < 4; i++) {
        k_gine16<<<GBLK, 256, 0, stream>>>(xh, ptr, er,
                                           g_ew + i * DIM, g_eb + i * DIM, g_eps + i,
                                           g_w1 + i * DIM * DIM, g_b1 + i * DIM,
                                           g_w2 + i * DIM * DIM, g_b2 + i * DIM,
                                           z, bpart);
        k_bnred<<<1, 1024, 0, stream>>>(bpart, bnstat + (i + 1) * 32);
        k_norm<<<nblocks, 256, 0, stream>>>(z, xh, bnstat + (i + 1) * 32,
                                            bn_gamma + (i + 1) * DIM, bn_beta + (i + 1) * DIM);
    }
    k_pool<<<(N_NODES + POOL_CHUNK - 1) / POOL_CHUNK, 256, 0, stream>>>(xh, batch, gsum, gcnt);
    k_xp<<<BGR, EMB, 0, stream>>>(gsum, gcnt, fc1_xp_w, fc1_xp_b, out + BGR * EMB);
}